// Round 10
// baseline (234.149 us; speedup 1.0000x reference)
//
#include <hip/hip_runtime.h>
#include <math.h>

typedef __attribute__((ext_vector_type(8))) short short8;
typedef __attribute__((ext_vector_type(4))) float f32x4;
typedef __attribute__((ext_vector_type(4))) unsigned short u16x4;

// Problem constants: B=2, L=2048, H=8, D=64, M=128.
constexpr int B_ = 2, L_ = 2048, H_ = 8, D_ = 64, M_ = 128;
constexpr int T_ = 64;            // chunk length
constexpr int C_ = L_ / T_;       // 32 chunks
constexpr int NBLK_ = B_ * H_ * C_;  // 512 = 2 blocks/CU x 256 CU (co-resident)
constexpr float DN_ = 0.35355339059327373f;     // 64^-0.25
constexpr float RATIO_ = 0.08838834764831845f;  // 1/sqrt(128)
constexpr float EPSV_ = 1e-6f;
constexpr float REPS_ = RATIO_ * EPSV_;   // ratio*eps: k' additive floor
constexpr float KEPS_ = 64.0f * REPS_;    // per-chunk ks eps mass

// LDS layout (unsigned short offsets). Peak 36352 shorts = 72704 B.
constexpr int XH_ = 0, XL_ = 4608, PH_ = 9216, PL_ = 18432, QP_ = 27648;
constexpr int VT_ = 0, SEST_ = 4608, KPE_ = 9216, KPT_ = 18432, KVST_ = 18432;

__device__ inline unsigned short f2bf(float x) {  // RNE float->bf16
  const unsigned u = __float_as_uint(x);
  return (unsigned short)((u + 0x7fffu + ((u >> 16) & 1u)) >> 16);
}
__device__ inline float bf2f(unsigned short h) {
  return __uint_as_float(((unsigned)h) << 16);
}

// Software grid barrier. Valid because all NBLK_ blocks are co-resident
// (grid = 2 blocks/CU exactly; LDS 76KB -> 2/CU, 8 waves/CU, VGPR <= 256).
// Device-scope atomics + agent fences handle cross-XCD L2 non-coherence;
// the spin MUST be an atomic load (plain load can spin on a stale L2 line).
__device__ inline void gbar(unsigned* cnt) {
  __syncthreads();
  if (threadIdx.x == 0) {
    __threadfence();  // release: write back this block's global stores
    __hip_atomic_fetch_add(cnt, 1u, __ATOMIC_RELEASE, __HIP_MEMORY_SCOPE_AGENT);
    while (__hip_atomic_load(cnt, __ATOMIC_ACQUIRE, __HIP_MEMORY_SCOPE_AGENT) <
           (unsigned)NBLK_) {
    }
  }
  __syncthreads();
  __threadfence();  // acquire: invalidate stale cache lines before reads
}

__global__ void init_bar_kernel(unsigned* bar) {
  if (threadIdx.x < 2) bar[threadIdx.x] = 0u;
}

// Single mega kernel: grid 512 = (bh, c). Phase A: feature maps + chunk sums
// (qp/kpE/VT stay in LDS). Phase B: cross-chunk prefix. Phase C: intra.
__global__ __launch_bounds__(256, 2) void mega_kernel(
    const float* __restrict__ q, const float* __restrict__ k,
    const float* __restrict__ P, const float* __restrict__ v,
    unsigned short* __restrict__ kvc16, float* __restrict__ ksc,
    float* __restrict__ vsum, float* __restrict__ blockmax,
    unsigned short* __restrict__ kvp16, unsigned* __restrict__ bar,
    float* __restrict__ out) {
  __shared__ __align__(16) unsigned short sm[36352];
  __shared__ float diag_s[T_];
  __shared__ float wred_s[2][T_];   // Q rowmax halves
  __shared__ float qs2_s[2][T_];    // Q row-sum halves (eps corrections)
  __shared__ float red4_s[4];
  __shared__ float denp_s[4][T_];
  __shared__ float den_s[T_];
  __shared__ float bm_s[C_];
  __shared__ float sc_s[C_];
  __shared__ float vs_s[2][C_];
  __shared__ float ksp_s[M_];

  const int sub = blockIdx.x;
  const int c = sub & 31, bh = sub >> 5;
  const int b = bh >> 3, h = bh & 7;
  const int tid = threadIdx.x;
  const int w = tid >> 6, lane = tid & 63;
  const int l15 = lane & 15, l16 = lane >> 4;
  const int rblk = (w >> 1) * 32, cblk = (w & 1) * 64;  // dash/KV quadrants

#define STAGE_X(xptr)                                                         \
  for (int i4 = tid; i4 < T_ * 16; i4 += 256) {                               \
    const int r = i4 >> 4, d0 = (i4 & 15) * 4;                                \
    f32x4 t4 = *reinterpret_cast<const f32x4*>(                               \
        &(xptr)[((size_t)(b * L_ + c * T_ + r) * H_ + h) * D_ + d0]);         \
    u16x4 hi, lo;                                                             \
    float sq = 0.f;                                                           \
    _Pragma("unroll") for (int j = 0; j < 4; ++j) {                           \
      const float xv = t4[j] * DN_;                                           \
      sq += xv * xv;                                                          \
      const unsigned short hb = f2bf(xv);                                     \
      hi[j] = hb;                                                             \
      lo[j] = f2bf(xv - bf2f(hb));                                            \
    }                                                                         \
    *reinterpret_cast<u16x4*>(&sm[XH_ + r * 72 + d0]) = hi;                   \
    *reinterpret_cast<u16x4*>(&sm[XL_ + r * 72 + d0]) = lo;                   \
    _Pragma("unroll") for (int off = 1; off < 16; off <<= 1)                  \
        sq += __shfl_xor(sq, off, 64);                                        \
    if ((tid & 15) == 0) diag_s[r] = sq;                                      \
  }

#define DASH_MFMA(accv)                                                       \
  _Pragma("unroll") for (int kk = 0; kk < 2; ++kk) {                          \
    short8 ah[2], al[2], bh8[4], bl8[4];                                      \
    _Pragma("unroll") for (int ti = 0; ti < 2; ++ti) {                        \
      ah[ti] = *reinterpret_cast<const short8*>(                              \
          &sm[XH_ + (rblk + ti * 16 + l15) * 72 + kk * 32 + l16 * 8]);        \
      al[ti] = *reinterpret_cast<const short8*>(                              \
          &sm[XL_ + (rblk + ti * 16 + l15) * 72 + kk * 32 + l16 * 8]);        \
    }                                                                         \
    _Pragma("unroll") for (int tj = 0; tj < 4; ++tj) {                        \
      bh8[tj] = *reinterpret_cast<const short8*>(                             \
          &sm[PH_ + (cblk + tj * 16 + l15) * 72 + kk * 32 + l16 * 8]);        \
      bl8[tj] = *reinterpret_cast<const short8*>(                             \
          &sm[PL_ + (cblk + tj * 16 + l15) * 72 + kk * 32 + l16 * 8]);        \
    }                                                                         \
    _Pragma("unroll") for (int ti = 0; ti < 2; ++ti)                          \
        _Pragma("unroll") for (int tj = 0; tj < 4; ++tj) {                    \
      accv[ti][tj] = __builtin_amdgcn_mfma_f32_16x16x32_bf16(                 \
          al[ti], bh8[tj], accv[ti][tj], 0, 0, 0);                            \
      accv[ti][tj] = __builtin_amdgcn_mfma_f32_16x16x32_bf16(                 \
          ah[ti], bl8[tj], accv[ti][tj], 0, 0, 0);                            \
      accv[ti][tj] = __builtin_amdgcn_mfma_f32_16x16x32_bf16(                 \
          ah[ti], bh8[tj], accv[ti][tj], 0, 0, 0);                            \
    }                                                                         \
  }

  // ================= Phase A =================
  for (int i4 = tid; i4 < M_ * 16; i4 += 256) {  // P hi/lo split inline
    const int m = i4 >> 4, d0 = (i4 & 15) * 4;
    const f32x4 t4 = *reinterpret_cast<const f32x4*>(&P[m * D_ + d0]);
    u16x4 hi, lo;
#pragma unroll
    for (int j = 0; j < 4; ++j) {
      hi[j] = f2bf(t4[j]);
      lo[j] = f2bf(t4[j] - bf2f(hi[j]));
    }
    *reinterpret_cast<u16x4*>(&sm[PH_ + m * 72 + d0]) = hi;
    *reinterpret_cast<u16x4*>(&sm[PL_ + m * 72 + d0]) = lo;
  }
  STAGE_X(q);
  __syncthreads();

  f32x4 acc[2][4];
#pragma unroll
  for (int i = 0; i < 2; ++i)
#pragma unroll
    for (int j = 0; j < 4; ++j) acc[i][j] = {0.f, 0.f, 0.f, 0.f};
  DASH_MFMA(acc);

  {  // Q per-row max over m
    float rmax[2][4];
#pragma unroll
    for (int ti = 0; ti < 2; ++ti)
#pragma unroll
      for (int j = 0; j < 4; ++j) {
        float m0 = fmaxf(fmaxf(acc[ti][0][j], acc[ti][1][j]),
                         fmaxf(acc[ti][2][j], acc[ti][3][j]));
#pragma unroll
        for (int off = 1; off < 16; off <<= 1)
          m0 = fmaxf(m0, __shfl_xor(m0, off, 64));
        rmax[ti][j] = m0;
      }
    if (l15 == 0) {
#pragma unroll
      for (int ti = 0; ti < 2; ++ti)
#pragma unroll
        for (int j = 0; j < 4; ++j)
          wred_s[w & 1][rblk + ti * 16 + l16 * 4 + j] = rmax[ti][j];
    }
  }
  __syncthreads();
  // Q epilogue: qp (with +eps) -> QP LDS (persistent) + qsum halves
#pragma unroll
  for (int ti = 0; ti < 2; ++ti)
#pragma unroll
    for (int j = 0; j < 4; ++j) {
      const int row = rblk + ti * 16 + l16 * 4 + j;
      const float sub2 =
          0.5f * diag_s[row] + fmaxf(wred_s[0][row], wred_s[1][row]);
      float qsp = 0.f;
#pragma unroll
      for (int tj = 0; tj < 4; ++tj) {
        const int col = cblk + tj * 16 + l15;
        const float qv = RATIO_ * (expf(acc[ti][tj][j] - sub2) + EPSV_);
        qsp += qv;
        sm[QP_ + row * 136 + col] = f2bf(qv);
      }
#pragma unroll
      for (int off = 1; off < 16; off <<= 1) qsp += __shfl_xor(qsp, off, 64);
      if (l15 == 0) qs2_s[w & 1][row] = qsp;
    }
  __syncthreads();  // diag reads done -> safe to restage X with k

  STAGE_X(k);
  __syncthreads();
#pragma unroll
  for (int i = 0; i < 2; ++i)
#pragma unroll
    for (int j = 0; j < 4; ++j) acc[i][j] = {0.f, 0.f, 0.f, 0.f};
  DASH_MFMA(acc);

  float bm = -INFINITY;
#pragma unroll
  for (int ti = 0; ti < 2; ++ti)
#pragma unroll
    for (int tj = 0; tj < 4; ++tj)
#pragma unroll
      for (int j = 0; j < 4; ++j) bm = fmaxf(bm, acc[ti][tj][j]);
#pragma unroll
  for (int off = 1; off < 64; off <<= 1) bm = fmaxf(bm, __shfl_xor(bm, off, 64));
  if (lane == 0) red4_s[w] = bm;
  __syncthreads();  // red4 visible AND all dash reads of PH/PL/XH/XL done
  const float lmax =
      fmaxf(fmaxf(red4_s[0], red4_s[1]), fmaxf(red4_s[2], red4_s[3]));
  if (tid == 0) blockmax[sub] = lmax;

  // kpE (NO eps, chunk-local units) -> KPE[t][m] + KPT[m][t]; V^T -> VT
#pragma unroll
  for (int ti = 0; ti < 2; ++ti)
#pragma unroll
    for (int j = 0; j < 4; ++j) {
      const int row = rblk + ti * 16 + l16 * 4 + j;
      const float sub2 = 0.5f * diag_s[row] + lmax;
#pragma unroll
      for (int tj = 0; tj < 4; ++tj) {
        const int col = cblk + tj * 16 + l15;
        const unsigned short us = f2bf(RATIO_ * expf(acc[ti][tj][j] - sub2));
        sm[KPE_ + row * 136 + col] = us;  // persists to phase C
        sm[KPT_ + col * 72 + row] = us;
      }
    }
  for (int i = tid; i < T_ * D_; i += 256) {
    const int t = i & 63, d = i >> 6;
    sm[VT_ + d * 72 + t] =  // persists to phase C
        f2bf(v[((size_t)(b * L_ + c * T_ + t) * H_ + h) * D_ + d]);
  }
  __syncthreads();

  // KV MFMA: KVE^T[d][m] = sum_t v[t,d]*kpE[t,m]
  f32x4 acc2[2][4];
#pragma unroll
  for (int i = 0; i < 2; ++i)
#pragma unroll
    for (int j = 0; j < 4; ++j) acc2[i][j] = {0.f, 0.f, 0.f, 0.f};
#pragma unroll
  for (int kk = 0; kk < 2; ++kk) {
    short8 av[2], bv[4];
#pragma unroll
    for (int ti = 0; ti < 2; ++ti)
      av[ti] = *reinterpret_cast<const short8*>(
          &sm[VT_ + (rblk + ti * 16 + l15) * 72 + kk * 32 + l16 * 8]);
#pragma unroll
    for (int tj = 0; tj < 4; ++tj)
      bv[tj] = *reinterpret_cast<const short8*>(
          &sm[KPT_ + (cblk + tj * 16 + l15) * 72 + kk * 32 + l16 * 8]);
#pragma unroll
    for (int ti = 0; ti < 2; ++ti)
#pragma unroll
      for (int tj = 0; tj < 4; ++tj)
        acc2[ti][tj] = __builtin_amdgcn_mfma_f32_16x16x32_bf16(
            av[ti], bv[tj], acc2[ti][tj], 0, 0, 0);
  }
  if (tid < M_) {  // ksE[m]
    float s = 0.f;
#pragma unroll
    for (int t8 = 0; t8 < 8; ++t8) {
      const short8 h8 =
          *reinterpret_cast<const short8*>(&sm[KPT_ + tid * 72 + t8 * 8]);
#pragma unroll
      for (int j = 0; j < 8; ++j) s += bf2f((unsigned short)h8[j]);
    }
    ksc[(size_t)(bh * C_ + c) * M_ + tid] = s;
  }
  if (tid >= 128 && tid < 128 + D_) {  // Vsum[d]
    const int d = tid - 128;
    float s = 0.f;
#pragma unroll
    for (int t8 = 0; t8 < 8; ++t8) {
      const short8 h8 =
          *reinterpret_cast<const short8*>(&sm[VT_ + d * 72 + t8 * 8]);
#pragma unroll
      for (int j = 0; j < 8; ++j) s += bf2f((unsigned short)h8[j]);
    }
    vsum[(size_t)(bh * C_ + c) * D_ + d] = s;
  }
  __syncthreads();  // KPT reads done -> repack over it
#pragma unroll
  for (int ti = 0; ti < 2; ++ti)
#pragma unroll
    for (int j = 0; j < 4; ++j) {
      const int row = rblk + ti * 16 + l16 * 4 + j;  // d
#pragma unroll
      for (int tj = 0; tj < 4; ++tj) {
        const int col = cblk + tj * 16 + l15;  // m
        sm[KVST_ + row * 136 + col] = f2bf(acc2[ti][tj][j]);
      }
    }
  __syncthreads();
  {
    unsigned short* ob = kvc16 + (size_t)(bh * C_ + c) * (M_ * D_);
    for (int i8 = tid; i8 < D_ * 16; i8 += 256) {
      const int d = i8 >> 4, m0 = (i8 & 15) * 8;
      *reinterpret_cast<short8*>(&ob[d * M_ + m0]) =
          *reinterpret_cast<const short8*>(&sm[KVST_ + d * 136 + m0]);
    }
  }
  gbar(&bar[0]);

  // ================= Phase B: prefix (block role = (bh, ej=c)) =============
  if (tid < C_) bm_s[tid] = blockmax[bh * C_ + tid];
  if (tid >= 64 && tid < 64 + 2 * C_) {
    const int t2 = tid - 64;
    const int ld = t2 >> 5, cc = t2 & 31;
    vs_s[ld][cc] = vsum[(size_t)(bh * C_ + cc) * D_ + c * 2 + ld];
  }
  __syncthreads();
  if (tid < C_) {
    float km = -INFINITY;
#pragma unroll
    for (int cc = 0; cc < C_; ++cc) km = fmaxf(km, bm_s[cc]);
    sc_s[tid] = expf(bm_s[tid] - km);
  }
  __syncthreads();
  {
    const int e = c * 256 + tid;  // element of [D][M]
    const int dl = tid >> 7;
    float vals[C_];
#pragma unroll
    for (int cc = 0; cc < C_; ++cc)
      vals[cc] =
          bf2f(kvc16[(size_t)(bh * C_ + cc) * (M_ * D_) + e]) * sc_s[cc] +
          REPS_ * vs_s[dl][cc];
    float run = 0.f;
#pragma unroll
    for (int cc = 0; cc < C_; ++cc) {
      const float t = vals[cc];
      vals[cc] = run;
      run += t;
    }
#pragma unroll
    for (int cc = 0; cc < C_; ++cc)
      kvp16[(size_t)(bh * C_ + cc) * (M_ * D_) + e] = f2bf(vals[cc]);
    if (c == 0 && tid < M_) {
      const int m = tid;
      float ks[C_];
#pragma unroll
      for (int cc = 0; cc < C_; ++cc)
        ks[cc] = ksc[(size_t)(bh * C_ + cc) * M_ + m] * sc_s[cc] + KEPS_;
      float rs = 0.f;
#pragma unroll
      for (int cc = 0; cc < C_; ++cc) {
        const float t = ks[cc];
        ks[cc] = rs;
        rs += t;
      }
#pragma unroll
      for (int cc = 0; cc < C_; ++cc)
        ksc[(size_t)(bh * C_ + cc) * M_ + m] = ks[cc];
    }
  }
  gbar(&bar[1]);

  // ================= Phase C: intra (qp/kpE/VT still in LDS) ===============
  if (tid < M_) ksp_s[tid] = ksc[(size_t)(bh * C_ + c) * M_ + tid];
  __syncthreads();
  const float sc = sc_s[c];

  // S MFMA: SE[t][t'] = sum_m qp[t][m]*kpE[t'][m]  (A=QP, B=KPE, both LDS)
  const int cs_ = (w & 1) * 32;
  f32x4 Sacc[2][2];
#pragma unroll
  for (int i = 0; i < 2; ++i)
#pragma unroll
    for (int j = 0; j < 2; ++j) Sacc[i][j] = {0.f, 0.f, 0.f, 0.f};
#pragma unroll
  for (int kk = 0; kk < 4; ++kk) {
    short8 af[2], bf[2];
#pragma unroll
    for (int ti = 0; ti < 2; ++ti)
      af[ti] = *reinterpret_cast<const short8*>(
          &sm[QP_ + (rblk + ti * 16 + l15) * 136 + kk * 32 + l16 * 8]);
#pragma unroll
    for (int tj = 0; tj < 2; ++tj)
      bf[tj] = *reinterpret_cast<const short8*>(
          &sm[KPE_ + (cs_ + tj * 16 + l15) * 136 + kk * 32 + l16 * 8]);
#pragma unroll
    for (int ti = 0; ti < 2; ++ti)
#pragma unroll
      for (int tj = 0; tj < 2; ++tj)
        Sacc[ti][tj] = __builtin_amdgcn_mfma_f32_16x16x32_bf16(
            af[ti], bf[tj], Sacc[ti][tj], 0, 0, 0);
  }
  // epilogue: S_true = sc*SE + REPS*qsum[row] (masked) -> SEST bf16
#pragma unroll
  for (int ti = 0; ti < 2; ++ti)
#pragma unroll
    for (int j = 0; j < 4; ++j) {
      const int row = rblk + ti * 16 + l16 * 4 + j;
      const float add = REPS_ * (qs2_s[0][row] + qs2_s[1][row]);
#pragma unroll
      for (int tj = 0; tj < 2; ++tj) {
        const int col = cs_ + tj * 16 + l15;
        const float sv = (col <= row) ? sc * Sacc[ti][tj][j] + add : 0.f;
        sm[SEST_ + row * 72 + col] = f2bf(sv);
      }
    }
  __syncthreads();

  {  // den partials: w0/w1 = S row-sum halves, w2/w3 = qp . ksp halves
    const int t = lane;
    float p = 0.f;
    if (w == 0) {
      for (int tp = 0; tp < 32; ++tp) p += bf2f(sm[SEST_ + t * 72 + tp]);
    } else if (w == 1) {
      for (int tp = 32; tp < 64; ++tp) p += bf2f(sm[SEST_ + t * 72 + tp]);
    } else if (w == 2) {
      for (int m = 0; m < 64; ++m)
        p += bf2f(sm[QP_ + t * 136 + m]) * ksp_s[m];
    } else {
      for (int m = 64; m < 128; ++m)
        p += bf2f(sm[QP_ + t * 136 + m]) * ksp_s[m];
    }
    denp_s[w][t] = p;
  }
  __syncthreads();
  if (tid < T_)
    den_s[tid] =
        denp_s[0][tid] + denp_s[1][tid] + denp_s[2][tid] + denp_s[3][tid];
  __syncthreads();

  const int dblk = (w & 1) * 32;
  const unsigned short* kvt = kvp16 + (size_t)(bh * C_ + c) * (M_ * D_);
  f32x4 Nacc[2][2];
#pragma unroll
  for (int i = 0; i < 2; ++i)
#pragma unroll
    for (int j = 0; j < 2; ++j) Nacc[i][j] = {0.f, 0.f, 0.f, 0.f};

#pragma unroll
  for (int kk = 0; kk < 2; ++kk) {  // S @ V^T  (both LDS)
    short8 af[2], bf[2];
#pragma unroll
    for (int ti = 0; ti < 2; ++ti)
      af[ti] = *reinterpret_cast<const short8*>(
          &sm[SEST_ + (rblk + ti * 16 + l15) * 72 + kk * 32 + l16 * 8]);
#pragma unroll
    for (int tj = 0; tj < 2; ++tj)
      bf[tj] = *reinterpret_cast<const short8*>(
          &sm[VT_ + (dblk + tj * 16 + l15) * 72 + kk * 32 + l16 * 8]);
#pragma unroll
    for (int ti = 0; ti < 2; ++ti)
#pragma unroll
      for (int tj = 0; tj < 2; ++tj)
        Nacc[ti][tj] = __builtin_amdgcn_mfma_f32_16x16x32_bf16(
            af[ti], bf[tj], Nacc[ti][tj], 0, 0, 0);
  }
#pragma unroll
  for (int kk = 0; kk < 4; ++kk) {  // qp @ KVp^T  (B-frags from global)
    short8 af[2], bf[2];
#pragma unroll
    for (int ti = 0; ti < 2; ++ti)
      af[ti] = *reinterpret_cast<const short8*>(
          &sm[QP_ + (rblk + ti * 16 + l15) * 136 + kk * 32 + l16 * 8]);
#pragma unroll
    for (int tj = 0; tj < 2; ++tj)
      bf[tj] = *reinterpret_cast<const short8*>(
          &kvt[(dblk + tj * 16 + l15) * M_ + kk * 32 + l16 * 8]);
#pragma unroll
    for (int ti = 0; ti < 2; ++ti)
#pragma unroll
      for (int tj = 0; tj < 2; ++tj)
        Nacc[ti][tj] = __builtin_amdgcn_mfma_f32_16x16x32_bf16(
            af[ti], bf[tj], Nacc[ti][tj], 0, 0, 0);
  }

#pragma unroll
  for (int ti = 0; ti < 2; ++ti)
#pragma unroll
    for (int j = 0; j < 4; ++j) {
      const int row = rblk + ti * 16 + l16 * 4 + j;
      const float r = 1.f / den_s[row];
      float* orow = out + ((size_t)(b * L_ + c * T_ + row) * H_ + h) * D_;
#pragma unroll
      for (int tj = 0; tj < 2; ++tj) {
        const int col = dblk + tj * 16 + l15;
        orow[col] = Nacc[ti][tj][j] * r;
      }
    }
#undef STAGE_X
#undef DASH_MFMA
}

extern "C" void kernel_launch(void* const* d_in, const int* in_sizes, int n_in,
                              void* d_out, int out_size, void* d_ws,
                              size_t ws_size, hipStream_t stream) {
  const float* q = (const float*)d_in[0];
  const float* k = (const float*)d_in[1];
  const float* v = (const float*)d_in[2];
  const float* P = (const float*)d_in[3];
  float* out = (float*)d_out;

  // Workspace (~17 MB): blockmax | ksc | vsum | kvc16 | kvp16 | bar
  float* ws = (float*)d_ws;
  float* blockmax = ws;                                   // 512
  float* ksc = blockmax + 512;                            // B*H*C*M = 65536
  float* vsum = ksc + (size_t)B_ * H_ * C_ * M_;          // B*H*C*D = 32768
  unsigned short* kvc16 = (unsigned short*)(vsum + (size_t)B_ * H_ * C_ * D_);
  unsigned short* kvp16 = kvc16 + (size_t)B_ * H_ * C_ * D_ * M_;
  unsigned* bar = (unsigned*)(kvp16 + (size_t)B_ * H_ * C_ * D_ * M_);

  init_bar_kernel<<<1, 64, 0, stream>>>(bar);
  mega_kernel<<<NBLK_, 256, 0, stream>>>(q, k, P, v, kvc16, ksc, vsum,
                                         blockmax, kvp16, bar, out);
}

// Round 11
// 182.376 us; speedup vs baseline: 1.2839x; 1.2839x over previous
//
#include <hip/hip_runtime.h>
#include <math.h>

typedef __attribute__((ext_vector_type(8))) short short8;
typedef __attribute__((ext_vector_type(4))) float f32x4;
typedef __attribute__((ext_vector_type(4))) unsigned short u16x4;

// Problem constants: B=2, L=2048, H=8, D=64, M=128.
constexpr int B_ = 2, L_ = 2048, H_ = 8, D_ = 64, M_ = 128;
constexpr int T_ = 64;            // chunk length
constexpr int C_ = L_ / T_;       // 32 chunks
constexpr int NBH_ = B_ * H_;     // 16 bh groups
constexpr int NBLK_ = NBH_ * C_;  // 512 = 2 blocks/CU x 256 CU (co-resident)
constexpr float DN_ = 0.35355339059327373f;     // 64^-0.25
constexpr float RATIO_ = 0.08838834764831845f;  // 1/sqrt(128)
constexpr float EPSV_ = 1e-6f;
constexpr float REPS_ = RATIO_ * EPSV_;   // ratio*eps: k' additive floor
constexpr float KEPS_ = 64.0f * REPS_;    // per-chunk ks eps mass

// LDS layout (unsigned short offsets). Peak 36352 shorts = 72704 B.
constexpr int XH_ = 0, XL_ = 4608, PH_ = 9216, PL_ = 18432, QP_ = 27648;
constexpr int VT_ = 0, SEST_ = 4608, KPE_ = 9216, KPT_ = 18432, KVST_ = 18432;

__device__ inline unsigned short f2bf(float x) {  // RNE float->bf16
  const unsigned u = __float_as_uint(x);
  return (unsigned short)((u + 0x7fffu + ((u >> 16) & 1u)) >> 16);
}
__device__ inline float bf2f(unsigned short h) {
  return __uint_as_float(((unsigned)h) << 16);
}

// Per-bh-group software barrier (32 blocks/group). All cross-block deps are
// within one bh group, so groups sync independently (round-10 lesson: one
// global counter + 0-delay ACQUIRE polling = 100us/barrier poll-storm convoy).
// Spin is RELAXED + s_sleep backoff; one ACQUIRE load + threadfence on exit
// gives cross-XCD visibility of the group's writes.
__device__ inline void gbar(unsigned* cnt, unsigned target) {
  __syncthreads();
  if (threadIdx.x == 0) {
    __threadfence();  // release this block's global stores
    __hip_atomic_fetch_add(cnt, 1u, __ATOMIC_RELEASE, __HIP_MEMORY_SCOPE_AGENT);
    while (__hip_atomic_load(cnt, __ATOMIC_RELAXED, __HIP_MEMORY_SCOPE_AGENT) <
           target) {
      __builtin_amdgcn_s_sleep(32);  // ~2k cycles between polls
    }
    (void)__hip_atomic_load(cnt, __ATOMIC_ACQUIRE, __HIP_MEMORY_SCOPE_AGENT);
  }
  __syncthreads();
  __threadfence();  // acquire: invalidate stale lines before reading
}

// bar layout: barA[bh] at bar[bh*16], barB[bh] at bar[256 + bh*16] (64B apart)
__global__ void init_bar_kernel(unsigned* bar) {
  const int i = blockIdx.x * 256 + threadIdx.x;
  if (i < 512) bar[i] = 0u;
}

// Single mega kernel: grid 512 = (bh, c). Phase A: feature maps + chunk sums
// (qp/kpE/VT stay in LDS). Phase B: cross-chunk prefix. Phase C: intra.
__global__ __launch_bounds__(256, 2) void mega_kernel(
    const float* __restrict__ q, const float* __restrict__ k,
    const float* __restrict__ P, const float* __restrict__ v,
    unsigned short* __restrict__ kvc16, float* __restrict__ ksc,
    float* __restrict__ vsum, float* __restrict__ blockmax,
    unsigned short* __restrict__ kvp16, unsigned* __restrict__ bar,
    float* __restrict__ out) {
  __shared__ __align__(16) unsigned short sm[36352];
  __shared__ float diag_s[T_];
  __shared__ float wred_s[2][T_];   // Q rowmax halves
  __shared__ float qs2_s[2][T_];    // Q row-sum halves (eps corrections)
  __shared__ float red4_s[4];
  __shared__ float denp_s[4][T_];
  __shared__ float den_s[T_];
  __shared__ float bm_s[C_];
  __shared__ float sc_s[C_];
  __shared__ float vs_s[2][C_];
  __shared__ float ksp_s[M_];

  const int sub = blockIdx.x;
  const int c = sub & 31, bh = sub >> 5;
  const int b = bh >> 3, h = bh & 7;
  const int tid = threadIdx.x;
  const int w = tid >> 6, lane = tid & 63;
  const int l15 = lane & 15, l16 = lane >> 4;
  const int rblk = (w >> 1) * 32, cblk = (w & 1) * 64;  // dash/KV quadrants

#define STAGE_X(xptr)                                                         \
  for (int i4 = tid; i4 < T_ * 16; i4 += 256) {                               \
    const int r = i4 >> 4, d0 = (i4 & 15) * 4;                                \
    f32x4 t4 = *reinterpret_cast<const f32x4*>(                               \
        &(xptr)[((size_t)(b * L_ + c * T_ + r) * H_ + h) * D_ + d0]);         \
    u16x4 hi, lo;                                                             \
    float sq = 0.f;                                                           \
    _Pragma("unroll") for (int j = 0; j < 4; ++j) {                           \
      const float xv = t4[j] * DN_;                                           \
      sq += xv * xv;                                                          \
      const unsigned short hb = f2bf(xv);                                     \
      hi[j] = hb;                                                             \
      lo[j] = f2bf(xv - bf2f(hb));                                            \
    }                                                                         \
    *reinterpret_cast<u16x4*>(&sm[XH_ + r * 72 + d0]) = hi;                   \
    *reinterpret_cast<u16x4*>(&sm[XL_ + r * 72 + d0]) = lo;                   \
    _Pragma("unroll") for (int off = 1; off < 16; off <<= 1)                  \
        sq += __shfl_xor(sq, off, 64);                                        \
    if ((tid & 15) == 0) diag_s[r] = sq;                                      \
  }

#define DASH_MFMA(accv)                                                       \
  _Pragma("unroll") for (int kk = 0; kk < 2; ++kk) {                          \
    short8 ah[2], al[2], bh8[4], bl8[4];                                      \
    _Pragma("unroll") for (int ti = 0; ti < 2; ++ti) {                        \
      ah[ti] = *reinterpret_cast<const short8*>(                              \
          &sm[XH_ + (rblk + ti * 16 + l15) * 72 + kk * 32 + l16 * 8]);        \
      al[ti] = *reinterpret_cast<const short8*>(                              \
          &sm[XL_ + (rblk + ti * 16 + l15) * 72 + kk * 32 + l16 * 8]);        \
    }                                                                         \
    _Pragma("unroll") for (int tj = 0; tj < 4; ++tj) {                        \
      bh8[tj] = *reinterpret_cast<const short8*>(                             \
          &sm[PH_ + (cblk + tj * 16 + l15) * 72 + kk * 32 + l16 * 8]);        \
      bl8[tj] = *reinterpret_cast<const short8*>(                             \
          &sm[PL_ + (cblk + tj * 16 + l15) * 72 + kk * 32 + l16 * 8]);        \
    }                                                                         \
    _Pragma("unroll") for (int ti = 0; ti < 2; ++ti)                          \
        _Pragma("unroll") for (int tj = 0; tj < 4; ++tj) {                    \
      accv[ti][tj] = __builtin_amdgcn_mfma_f32_16x16x32_bf16(                 \
          al[ti], bh8[tj], accv[ti][tj], 0, 0, 0);                            \
      accv[ti][tj] = __builtin_amdgcn_mfma_f32_16x16x32_bf16(                 \
          ah[ti], bl8[tj], accv[ti][tj], 0, 0, 0);                            \
      accv[ti][tj] = __builtin_amdgcn_mfma_f32_16x16x32_bf16(                 \
          ah[ti], bh8[tj], accv[ti][tj], 0, 0, 0);                            \
    }                                                                         \
  }

  // ================= Phase A =================
  for (int i4 = tid; i4 < M_ * 16; i4 += 256) {  // P hi/lo split inline
    const int m = i4 >> 4, d0 = (i4 & 15) * 4;
    const f32x4 t4 = *reinterpret_cast<const f32x4*>(&P[m * D_ + d0]);
    u16x4 hi, lo;
#pragma unroll
    for (int j = 0; j < 4; ++j) {
      hi[j] = f2bf(t4[j]);
      lo[j] = f2bf(t4[j] - bf2f(hi[j]));
    }
    *reinterpret_cast<u16x4*>(&sm[PH_ + m * 72 + d0]) = hi;
    *reinterpret_cast<u16x4*>(&sm[PL_ + m * 72 + d0]) = lo;
  }
  STAGE_X(q);
  __syncthreads();

  f32x4 acc[2][4];
#pragma unroll
  for (int i = 0; i < 2; ++i)
#pragma unroll
    for (int j = 0; j < 4; ++j) acc[i][j] = {0.f, 0.f, 0.f, 0.f};
  DASH_MFMA(acc);

  {  // Q per-row max over m
    float rmax[2][4];
#pragma unroll
    for (int ti = 0; ti < 2; ++ti)
#pragma unroll
      for (int j = 0; j < 4; ++j) {
        float m0 = fmaxf(fmaxf(acc[ti][0][j], acc[ti][1][j]),
                         fmaxf(acc[ti][2][j], acc[ti][3][j]));
#pragma unroll
        for (int off = 1; off < 16; off <<= 1)
          m0 = fmaxf(m0, __shfl_xor(m0, off, 64));
        rmax[ti][j] = m0;
      }
    if (l15 == 0) {
#pragma unroll
      for (int ti = 0; ti < 2; ++ti)
#pragma unroll
        for (int j = 0; j < 4; ++j)
          wred_s[w & 1][rblk + ti * 16 + l16 * 4 + j] = rmax[ti][j];
    }
  }
  __syncthreads();
  // Q epilogue: qp (with +eps) -> QP LDS (persistent) + qsum halves
#pragma unroll
  for (int ti = 0; ti < 2; ++ti)
#pragma unroll
    for (int j = 0; j < 4; ++j) {
      const int row = rblk + ti * 16 + l16 * 4 + j;
      const float sub2 =
          0.5f * diag_s[row] + fmaxf(wred_s[0][row], wred_s[1][row]);
      float qsp = 0.f;
#pragma unroll
      for (int tj = 0; tj < 4; ++tj) {
        const int col = cblk + tj * 16 + l15;
        const float qv = RATIO_ * (expf(acc[ti][tj][j] - sub2) + EPSV_);
        qsp += qv;
        sm[QP_ + row * 136 + col] = f2bf(qv);
      }
#pragma unroll
      for (int off = 1; off < 16; off <<= 1) qsp += __shfl_xor(qsp, off, 64);
      if (l15 == 0) qs2_s[w & 1][row] = qsp;
    }
  __syncthreads();  // diag reads done -> safe to restage X with k

  STAGE_X(k);
  __syncthreads();
#pragma unroll
  for (int i = 0; i < 2; ++i)
#pragma unroll
    for (int j = 0; j < 4; ++j) acc[i][j] = {0.f, 0.f, 0.f, 0.f};
  DASH_MFMA(acc);

  float bm = -INFINITY;
#pragma unroll
  for (int ti = 0; ti < 2; ++ti)
#pragma unroll
    for (int tj = 0; tj < 4; ++tj)
#pragma unroll
      for (int j = 0; j < 4; ++j) bm = fmaxf(bm, acc[ti][tj][j]);
#pragma unroll
  for (int off = 1; off < 64; off <<= 1) bm = fmaxf(bm, __shfl_xor(bm, off, 64));
  if (lane == 0) red4_s[w] = bm;
  __syncthreads();  // red4 visible AND all dash reads of PH/PL/XH/XL done
  const float lmax =
      fmaxf(fmaxf(red4_s[0], red4_s[1]), fmaxf(red4_s[2], red4_s[3]));
  if (tid == 0) blockmax[sub] = lmax;

  // kpE (NO eps, chunk-local units) -> KPE[t][m] + KPT[m][t]; V^T -> VT
#pragma unroll
  for (int ti = 0; ti < 2; ++ti)
#pragma unroll
    for (int j = 0; j < 4; ++j) {
      const int row = rblk + ti * 16 + l16 * 4 + j;
      const float sub2 = 0.5f * diag_s[row] + lmax;
#pragma unroll
      for (int tj = 0; tj < 4; ++tj) {
        const int col = cblk + tj * 16 + l15;
        const unsigned short us = f2bf(RATIO_ * expf(acc[ti][tj][j] - sub2));
        sm[KPE_ + row * 136 + col] = us;  // persists to phase C
        sm[KPT_ + col * 72 + row] = us;
      }
    }
  for (int i = tid; i < T_ * D_; i += 256) {
    const int t = i & 63, d = i >> 6;
    sm[VT_ + d * 72 + t] =  // persists to phase C
        f2bf(v[((size_t)(b * L_ + c * T_ + t) * H_ + h) * D_ + d]);
  }
  __syncthreads();

  // KV MFMA: KVE^T[d][m] = sum_t v[t,d]*kpE[t,m]
  f32x4 acc2[2][4];
#pragma unroll
  for (int i = 0; i < 2; ++i)
#pragma unroll
    for (int j = 0; j < 4; ++j) acc2[i][j] = {0.f, 0.f, 0.f, 0.f};
#pragma unroll
  for (int kk = 0; kk < 2; ++kk) {
    short8 av[2], bv[4];
#pragma unroll
    for (int ti = 0; ti < 2; ++ti)
      av[ti] = *reinterpret_cast<const short8*>(
          &sm[VT_ + (rblk + ti * 16 + l15) * 72 + kk * 32 + l16 * 8]);
#pragma unroll
    for (int tj = 0; tj < 4; ++tj)
      bv[tj] = *reinterpret_cast<const short8*>(
          &sm[KPT_ + (cblk + tj * 16 + l15) * 72 + kk * 32 + l16 * 8]);
#pragma unroll
    for (int ti = 0; ti < 2; ++ti)
#pragma unroll
      for (int tj = 0; tj < 4; ++tj)
        acc2[ti][tj] = __builtin_amdgcn_mfma_f32_16x16x32_bf16(
            av[ti], bv[tj], acc2[ti][tj], 0, 0, 0);
  }
  if (tid < M_) {  // ksE[m]
    float s = 0.f;
#pragma unroll
    for (int t8 = 0; t8 < 8; ++t8) {
      const short8 h8 =
          *reinterpret_cast<const short8*>(&sm[KPT_ + tid * 72 + t8 * 8]);
#pragma unroll
      for (int j = 0; j < 8; ++j) s += bf2f((unsigned short)h8[j]);
    }
    ksc[(size_t)(bh * C_ + c) * M_ + tid] = s;
  }
  if (tid >= 128 && tid < 128 + D_) {  // Vsum[d]
    const int d = tid - 128;
    float s = 0.f;
#pragma unroll
    for (int t8 = 0; t8 < 8; ++t8) {
      const short8 h8 =
          *reinterpret_cast<const short8*>(&sm[VT_ + d * 72 + t8 * 8]);
#pragma unroll
      for (int j = 0; j < 8; ++j) s += bf2f((unsigned short)h8[j]);
    }
    vsum[(size_t)(bh * C_ + c) * D_ + d] = s;
  }
  __syncthreads();  // KPT reads done -> repack over it
#pragma unroll
  for (int ti = 0; ti < 2; ++ti)
#pragma unroll
    for (int j = 0; j < 4; ++j) {
      const int row = rblk + ti * 16 + l16 * 4 + j;  // d
#pragma unroll
      for (int tj = 0; tj < 4; ++tj) {
        const int col = cblk + tj * 16 + l15;  // m
        sm[KVST_ + row * 136 + col] = f2bf(acc2[ti][tj][j]);
      }
    }
  __syncthreads();
  {
    unsigned short* ob = kvc16 + (size_t)(bh * C_ + c) * (M_ * D_);
    for (int i8 = tid; i8 < D_ * 16; i8 += 256) {
      const int d = i8 >> 4, m0 = (i8 & 15) * 8;
      *reinterpret_cast<short8*>(&ob[d * M_ + m0]) =
          *reinterpret_cast<const short8*>(&sm[KVST_ + d * 136 + m0]);
    }
  }
  gbar(&bar[bh * 16], C_);

  // ================= Phase B: prefix (block role = (bh, ej=c)) =============
  if (tid < C_) bm_s[tid] = blockmax[bh * C_ + tid];
  if (tid >= 64 && tid < 64 + 2 * C_) {
    const int t2 = tid - 64;
    const int ld = t2 >> 5, cc = t2 & 31;
    vs_s[ld][cc] = vsum[(size_t)(bh * C_ + cc) * D_ + c * 2 + ld];
  }
  __syncthreads();
  if (tid < C_) {
    float km = -INFINITY;
#pragma unroll
    for (int cc = 0; cc < C_; ++cc) km = fmaxf(km, bm_s[cc]);
    sc_s[tid] = expf(bm_s[tid] - km);
  }
  __syncthreads();
  {
    const int e = c * 256 + tid;  // element of [D][M]
    const int dl = tid >> 7;
    float vals[C_];
#pragma unroll
    for (int cc = 0; cc < C_; ++cc)
      vals[cc] =
          bf2f(kvc16[(size_t)(bh * C_ + cc) * (M_ * D_) + e]) * sc_s[cc] +
          REPS_ * vs_s[dl][cc];
    float run = 0.f;
#pragma unroll
    for (int cc = 0; cc < C_; ++cc) {
      const float t = vals[cc];
      vals[cc] = run;
      run += t;
    }
#pragma unroll
    for (int cc = 0; cc < C_; ++cc)
      kvp16[(size_t)(bh * C_ + cc) * (M_ * D_) + e] = f2bf(vals[cc]);
    if (c == 0 && tid < M_) {
      const int m = tid;
      float ks[C_];
#pragma unroll
      for (int cc = 0; cc < C_; ++cc)
        ks[cc] = ksc[(size_t)(bh * C_ + cc) * M_ + m] * sc_s[cc] + KEPS_;
      float rs = 0.f;
#pragma unroll
      for (int cc = 0; cc < C_; ++cc) {
        const float t = ks[cc];
        ks[cc] = rs;
        rs += t;
      }
#pragma unroll
      for (int cc = 0; cc < C_; ++cc)
        ksc[(size_t)(bh * C_ + cc) * M_ + m] = ks[cc];
    }
  }
  gbar(&bar[256 + bh * 16], C_);

  // ================= Phase C: intra (qp/kpE/VT still in LDS) ===============
  if (tid < M_) ksp_s[tid] = ksc[(size_t)(bh * C_ + c) * M_ + tid];
  __syncthreads();
  const float sc = sc_s[c];

  // S MFMA: SE[t][t'] = sum_m qp[t][m]*kpE[t'][m]  (A=QP, B=KPE, both LDS)
  const int cs_ = (w & 1) * 32;
  f32x4 Sacc[2][2];
#pragma unroll
  for (int i = 0; i < 2; ++i)
#pragma unroll
    for (int j = 0; j < 2; ++j) Sacc[i][j] = {0.f, 0.f, 0.f, 0.f};
#pragma unroll
  for (int kk = 0; kk < 4; ++kk) {
    short8 af[2], bf[2];
#pragma unroll
    for (int ti = 0; ti < 2; ++ti)
      af[ti] = *reinterpret_cast<const short8*>(
          &sm[QP_ + (rblk + ti * 16 + l15) * 136 + kk * 32 + l16 * 8]);
#pragma unroll
    for (int tj = 0; tj < 2; ++tj)
      bf[tj] = *reinterpret_cast<const short8*>(
          &sm[KPE_ + (cs_ + tj * 16 + l15) * 136 + kk * 32 + l16 * 8]);
#pragma unroll
    for (int ti = 0; ti < 2; ++ti)
#pragma unroll
      for (int tj = 0; tj < 2; ++tj)
        Sacc[ti][tj] = __builtin_amdgcn_mfma_f32_16x16x32_bf16(
            af[ti], bf[tj], Sacc[ti][tj], 0, 0, 0);
  }
  // epilogue: S_true = sc*SE + REPS*qsum[row] (masked) -> SEST bf16
#pragma unroll
  for (int ti = 0; ti < 2; ++ti)
#pragma unroll
    for (int j = 0; j < 4; ++j) {
      const int row = rblk + ti * 16 + l16 * 4 + j;
      const float add = REPS_ * (qs2_s[0][row] + qs2_s[1][row]);
#pragma unroll
      for (int tj = 0; tj < 2; ++tj) {
        const int col = cs_ + tj * 16 + l15;
        const float sv = (col <= row) ? sc * Sacc[ti][tj][j] + add : 0.f;
        sm[SEST_ + row * 72 + col] = f2bf(sv);
      }
    }
  __syncthreads();

  {  // den partials: w0/w1 = S row-sum halves, w2/w3 = qp . ksp halves
    const int t = lane;
    float p = 0.f;
    if (w == 0) {
      for (int tp = 0; tp < 32; ++tp) p += bf2f(sm[SEST_ + t * 72 + tp]);
    } else if (w == 1) {
      for (int tp = 32; tp < 64; ++tp) p += bf2f(sm[SEST_ + t * 72 + tp]);
    } else if (w == 2) {
      for (int m = 0; m < 64; ++m)
        p += bf2f(sm[QP_ + t * 136 + m]) * ksp_s[m];
    } else {
      for (int m = 64; m < 128; ++m)
        p += bf2f(sm[QP_ + t * 136 + m]) * ksp_s[m];
    }
    denp_s[w][t] = p;
  }
  __syncthreads();
  if (tid < T_)
    den_s[tid] =
        denp_s[0][tid] + denp_s[1][tid] + denp_s[2][tid] + denp_s[3][tid];
  __syncthreads();

  const int dblk = (w & 1) * 32;
  const unsigned short* kvt = kvp16 + (size_t)(bh * C_ + c) * (M_ * D_);
  f32x4 Nacc[2][2];
#pragma unroll
  for (int i = 0; i < 2; ++i)
#pragma unroll
    for (int j = 0; j < 2; ++j) Nacc[i][j] = {0.f, 0.f, 0.f, 0.f};

#pragma unroll
  for (int kk = 0; kk < 2; ++kk) {  // S @ V^T  (both LDS)
    short8 af[2], bf[2];
#pragma unroll
    for (int ti = 0; ti < 2; ++ti)
      af[ti] = *reinterpret_cast<const short8*>(
          &sm[SEST_ + (rblk + ti * 16 + l15) * 72 + kk * 32 + l16 * 8]);
#pragma unroll
    for (int tj = 0; tj < 2; ++tj)
      bf[tj] = *reinterpret_cast<const short8*>(
          &sm[VT_ + (dblk + tj * 16 + l15) * 72 + kk * 32 + l16 * 8]);
#pragma unroll
    for (int ti = 0; ti < 2; ++ti)
#pragma unroll
      for (int tj = 0; tj < 2; ++tj)
        Nacc[ti][tj] = __builtin_amdgcn_mfma_f32_16x16x32_bf16(
            af[ti], bf[tj], Nacc[ti][tj], 0, 0, 0);
  }
#pragma unroll
  for (int kk = 0; kk < 4; ++kk) {  // qp @ KVp^T  (B-frags from global)
    short8 af[2], bf[2];
#pragma unroll
    for (int ti = 0; ti < 2; ++ti)
      af[ti] = *reinterpret_cast<const short8*>(
          &sm[QP_ + (rblk + ti * 16 + l15) * 136 + kk * 32 + l16 * 8]);
#pragma unroll
    for (int tj = 0; tj < 2; ++tj)
      bf[tj] = *reinterpret_cast<const short8*>(
          &kvt[(dblk + tj * 16 + l15) * M_ + kk * 32 + l16 * 8]);
#pragma unroll
    for (int ti = 0; ti < 2; ++ti)
#pragma unroll
      for (int tj = 0; tj < 2; ++tj)
        Nacc[ti][tj] = __builtin_amdgcn_mfma_f32_16x16x32_bf16(
            af[ti], bf[tj], Nacc[ti][tj], 0, 0, 0);
  }

#pragma unroll
  for (int ti = 0; ti < 2; ++ti)
#pragma unroll
    for (int j = 0; j < 4; ++j) {
      const int row = rblk + ti * 16 + l16 * 4 + j;
      const float r = 1.f / den_s[row];
      float* orow = out + ((size_t)(b * L_ + c * T_ + row) * H_ + h) * D_;
#pragma unroll
      for (int tj = 0; tj < 2; ++tj) {
        const int col = dblk + tj * 16 + l15;
        orow[col] = Nacc[ti][tj][j] * r;
      }
    }
#undef STAGE_X
#undef DASH_MFMA
}

extern "C" void kernel_launch(void* const* d_in, const int* in_sizes, int n_in,
                              void* d_out, int out_size, void* d_ws,
                              size_t ws_size, hipStream_t stream) {
  const float* q = (const float*)d_in[0];
  const float* k = (const float*)d_in[1];
  const float* v = (const float*)d_in[2];
  const float* P = (const float*)d_in[3];
  float* out = (float*)d_out;

  // Workspace (~17 MB): blockmax | ksc | vsum | kvc16 | kvp16 | bar
  float* ws = (float*)d_ws;
  float* blockmax = ws;                                   // 512
  float* ksc = blockmax + 512;                            // B*H*C*M = 65536
  float* vsum = ksc + (size_t)B_ * H_ * C_ * M_;          // B*H*C*D = 32768
  unsigned short* kvc16 = (unsigned short*)(vsum + (size_t)B_ * H_ * C_ * D_);
  unsigned short* kvp16 = kvc16 + (size_t)B_ * H_ * C_ * D_ * M_;
  unsigned* bar = (unsigned*)(kvp16 + (size_t)B_ * H_ * C_ * D_ * M_);

  init_bar_kernel<<<2, 256, 0, stream>>>(bar);
  mega_kernel<<<NBLK_, 256, 0, stream>>>(q, k, P, v, kvc16, ksc, vsum,
                                         blockmax, kvp16, bar, out);
}

// Round 13
// 44.491 us; speedup vs baseline: 5.2628x; 4.0991x over previous
//
#include <hip/hip_runtime.h>
#include <math.h>

typedef __attribute__((ext_vector_type(8))) short short8;
typedef __attribute__((ext_vector_type(4))) float f32x4;
typedef __attribute__((ext_vector_type(4))) unsigned short u16x4;

// Problem constants: B=2, L=2048, H=8, D=64, M=128.
constexpr int B_ = 2, L_ = 2048, H_ = 8, D_ = 64, M_ = 128;
constexpr int T_ = 64;            // chunk length
constexpr int C_ = L_ / T_;       // 32 chunks
constexpr float DN_ = 0.35355339059327373f;     // 64^-0.25
constexpr float RATIO_ = 0.08838834764831845f;  // 1/sqrt(128)
constexpr float EPSV_ = 1e-6f;
constexpr float REPS_ = RATIO_ * EPSV_;   // ratio*eps: k' additive floor
constexpr float KEPS_ = 64.0f * REPS_;    // per-chunk ks eps mass

__device__ inline unsigned short f2bf(float x) {  // RNE float->bf16
  const unsigned u = __float_as_uint(x);
  return (unsigned short)((u + 0x7fffu + ((u >> 16) & 1u)) >> 16);
}
__device__ inline float bf2f(unsigned short h) {
  return __uint_as_float(((unsigned)h) << 16);
}

// Fused feature kernel, grid 512 = (bh, chunk). R7 structure + T14 prefetch:
// K-tile and V-tile are loaded into REGISTERS before the Q-phase compute, so
// the second/third HBM round-trips hide under Q MFMA/epilogue. P hi/lo split
// is inline (no psplit kernel).
__global__ __launch_bounds__(256, 2) void feat_kernel(
    const float* __restrict__ q, const float* __restrict__ k,
    const float* __restrict__ P, const float* __restrict__ v,
    unsigned short* __restrict__ qp16, unsigned short* __restrict__ kp16,
    unsigned short* __restrict__ kvc16, float* __restrict__ ksc,
    unsigned short* __restrict__ vt16, float* __restrict__ blockmax,
    float* __restrict__ vsum) {
  // flat LDS (shorts): XH[64x72]@0, XL[64x72]@4608, PH[128x72]@9216,
  // PL[128x72]@18432. Aliases: QPST[64][136]@0 (over XH+XL);
  // VT[64][72]@0 (over XH); KPT[128][72]@9216 (over PH);
  // KVST[64][136]@18432 (over PL).
  __shared__ __align__(16) unsigned short sm[27648];
  __shared__ float diag_s[T_];
  __shared__ float wred_s[2][T_];
  __shared__ float red4_s[4];

  const int sub = blockIdx.x;
  const int c = sub % C_, bh = sub / C_;
  const int b = bh >> 3, h = bh & 7;
  const int tid = threadIdx.x;
  const int w = tid >> 6, lane = tid & 63;
  const int l15 = lane & 15, l16 = lane >> 4;
  const int rblk = (w >> 1) * 32, cblk = (w & 1) * 64;

  // ---- T14 prefetch: issue K and V tile loads FIRST (hide under Q phase) --
  f32x4 kreg[4], vreg[4];
#pragma unroll
  for (int it = 0; it < 4; ++it) {
    const int i4 = tid + 256 * it;
    const int r = i4 >> 4, d0 = (i4 & 15) * 4;
    kreg[it] = *reinterpret_cast<const f32x4*>(
        &k[((size_t)(b * L_ + c * T_ + r) * H_ + h) * D_ + d0]);
    vreg[it] = *reinterpret_cast<const f32x4*>(
        &v[((size_t)(b * L_ + c * T_ + r) * H_ + h) * D_ + d0]);
  }

  // stage P with inline hi/lo split
  for (int i4 = tid; i4 < M_ * 16; i4 += 256) {
    const int m = i4 >> 4, d0 = (i4 & 15) * 4;
    const f32x4 t4 = *reinterpret_cast<const f32x4*>(&P[m * D_ + d0]);
    u16x4 hi, lo;
#pragma unroll
    for (int j = 0; j < 4; ++j) {
      hi[j] = f2bf(t4[j]);
      lo[j] = f2bf(t4[j] - bf2f(hi[j]));
    }
    *reinterpret_cast<u16x4*>(&sm[9216 + m * 72 + d0]) = hi;
    *reinterpret_cast<u16x4*>(&sm[18432 + m * 72 + d0]) = lo;
  }
  // stage X(q) from global
  for (int i4 = tid; i4 < T_ * 16; i4 += 256) {
    const int r = i4 >> 4, d0 = (i4 & 15) * 4;
    f32x4 t4 = *reinterpret_cast<const f32x4*>(
        &q[((size_t)(b * L_ + c * T_ + r) * H_ + h) * D_ + d0]);
    u16x4 hi, lo;
    float sq = 0.f;
#pragma unroll
    for (int j = 0; j < 4; ++j) {
      const float xv = t4[j] * DN_;
      sq += xv * xv;
      const unsigned short hb = f2bf(xv);
      hi[j] = hb;
      lo[j] = f2bf(xv - bf2f(hb));
    }
    *reinterpret_cast<u16x4*>(&sm[r * 72 + d0]) = hi;
    *reinterpret_cast<u16x4*>(&sm[4608 + r * 72 + d0]) = lo;
#pragma unroll
    for (int off = 1; off < 16; off <<= 1) sq += __shfl_xor(sq, off, 64);
    if ((tid & 15) == 0) diag_s[r] = sq;
  }

#define DASH_MFMA(accv)                                                       \
  _Pragma("unroll") for (int kk = 0; kk < 2; ++kk) {                          \
    short8 ah[2], al[2], bh8[4], bl8[4];                                      \
    _Pragma("unroll") for (int ti = 0; ti < 2; ++ti) {                        \
      ah[ti] = *reinterpret_cast<const short8*>(                              \
          &sm[(rblk + ti * 16 + l15) * 72 + kk * 32 + l16 * 8]);              \
      al[ti] = *reinterpret_cast<const short8*>(                              \
          &sm[4608 + (rblk + ti * 16 + l15) * 72 + kk * 32 + l16 * 8]);       \
    }                                                                         \
    _Pragma("unroll") for (int tj = 0; tj < 4; ++tj) {                        \
      bh8[tj] = *reinterpret_cast<const short8*>(                             \
          &sm[9216 + (cblk + tj * 16 + l15) * 72 + kk * 32 + l16 * 8]);       \
      bl8[tj] = *reinterpret_cast<const short8*>(                             \
          &sm[18432 + (cblk + tj * 16 + l15) * 72 + kk * 32 + l16 * 8]);      \
    }                                                                         \
    _Pragma("unroll") for (int ti = 0; ti < 2; ++ti)                          \
        _Pragma("unroll") for (int tj = 0; tj < 4; ++tj) {                    \
      accv[ti][tj] = __builtin_amdgcn_mfma_f32_16x16x32_bf16(                 \
          al[ti], bh8[tj], accv[ti][tj], 0, 0, 0);                            \
      accv[ti][tj] = __builtin_amdgcn_mfma_f32_16x16x32_bf16(                 \
          ah[ti], bl8[tj], accv[ti][tj], 0, 0, 0);                            \
      accv[ti][tj] = __builtin_amdgcn_mfma_f32_16x16x32_bf16(                 \
          ah[ti], bh8[tj], accv[ti][tj], 0, 0, 0);                            \
    }                                                                         \
  }

  // ======== Q phase ========
  __syncthreads();
  f32x4 acc[2][4];
#pragma unroll
  for (int i = 0; i < 2; ++i)
#pragma unroll
    for (int j = 0; j < 4; ++j) acc[i][j] = {0.f, 0.f, 0.f, 0.f};
  DASH_MFMA(acc);

  {  // per-row stab
    float rmax[2][4];
#pragma unroll
    for (int ti = 0; ti < 2; ++ti)
#pragma unroll
      for (int j = 0; j < 4; ++j) {
        float m0 = fmaxf(fmaxf(acc[ti][0][j], acc[ti][1][j]),
                         fmaxf(acc[ti][2][j], acc[ti][3][j]));
#pragma unroll
        for (int off = 1; off < 16; off <<= 1)
          m0 = fmaxf(m0, __shfl_xor(m0, off, 64));
        rmax[ti][j] = m0;
      }
    if (l15 == 0) {
#pragma unroll
      for (int ti = 0; ti < 2; ++ti)
#pragma unroll
        for (int j = 0; j < 4; ++j)
          wred_s[w & 1][rblk + ti * 16 + l16 * 4 + j] = rmax[ti][j];
    }
    __syncthreads();  // wred visible; all MFMA reads of XH/XL done
#pragma unroll
    for (int ti = 0; ti < 2; ++ti)
#pragma unroll
      for (int j = 0; j < 4; ++j) {
        const int row = rblk + ti * 16 + l16 * 4 + j;
        const float sub2 =
            0.5f * diag_s[row] + fmaxf(wred_s[0][row], wred_s[1][row]);
#pragma unroll
        for (int tj = 0; tj < 4; ++tj) {
          const int col = cblk + tj * 16 + l15;
          sm[row * 136 + col] =  // QPST repack (aliases XH/XL)
              f2bf(RATIO_ * (expf(acc[ti][tj][j] - sub2) + EPSV_));
        }
      }
    __syncthreads();
    unsigned short* outr = qp16 + ((size_t)bh * L_ + c * T_) * M_;
    for (int i8 = tid; i8 < T_ * 16; i8 += 256) {
      const int row = i8 >> 4, m0 = (i8 & 15) * 8;
      *reinterpret_cast<short8*>(&outr[row * M_ + m0]) =
          *reinterpret_cast<const short8*>(&sm[row * 136 + m0]);
    }
  }
  __syncthreads();  // QPST reads done; safe to restage X

  // ======== K phase (staged from prefetched registers) ========
#pragma unroll
  for (int it = 0; it < 4; ++it) {
    const int i4 = tid + 256 * it;
    const int r = i4 >> 4, d0 = (i4 & 15) * 4;
    u16x4 hi, lo;
    float sq = 0.f;
#pragma unroll
    for (int j = 0; j < 4; ++j) {
      const float xv = kreg[it][j] * DN_;
      sq += xv * xv;
      const unsigned short hb = f2bf(xv);
      hi[j] = hb;
      lo[j] = f2bf(xv - bf2f(hb));
    }
    *reinterpret_cast<u16x4*>(&sm[r * 72 + d0]) = hi;
    *reinterpret_cast<u16x4*>(&sm[4608 + r * 72 + d0]) = lo;
#pragma unroll
    for (int off = 1; off < 16; off <<= 1) sq += __shfl_xor(sq, off, 64);
    if ((tid & 15) == 0) diag_s[r] = sq;
  }
  __syncthreads();
#pragma unroll
  for (int i = 0; i < 2; ++i)
#pragma unroll
    for (int j = 0; j < 4; ++j) acc[i][j] = {0.f, 0.f, 0.f, 0.f};
  DASH_MFMA(acc);

  float bm = -INFINITY;
#pragma unroll
  for (int ti = 0; ti < 2; ++ti)
#pragma unroll
    for (int tj = 0; tj < 4; ++tj)
#pragma unroll
      for (int j = 0; j < 4; ++j) bm = fmaxf(bm, acc[ti][tj][j]);
#pragma unroll
  for (int off = 1; off < 64; off <<= 1) bm = fmaxf(bm, __shfl_xor(bm, off, 64));
  if (lane == 0) red4_s[w] = bm;
  __syncthreads();  // red4 visible AND all MFMA reads of PH/XH done
  const float lmax =
      fmaxf(fmaxf(red4_s[0], red4_s[1]), fmaxf(red4_s[2], red4_s[3]));
  if (tid == 0) blockmax[sub] = lmax;

  // kpE (NO eps) -> global + KPT (aliases PH); V^T from vreg (aliases XH)
  unsigned short* kpr = kp16 + ((size_t)bh * L_ + c * T_) * M_;
#pragma unroll
  for (int ti = 0; ti < 2; ++ti)
#pragma unroll
    for (int j = 0; j < 4; ++j) {
      const int row = rblk + ti * 16 + l16 * 4 + j;
      const float sub2 = 0.5f * diag_s[row] + lmax;
#pragma unroll
      for (int tj = 0; tj < 4; ++tj) {
        const int col = cblk + tj * 16 + l15;
        const unsigned short us = f2bf(RATIO_ * expf(acc[ti][tj][j] - sub2));
        kpr[row * M_ + col] = us;
        sm[9216 + col * 72 + row] = us;  // KPT[m][t]
      }
    }
#pragma unroll
  for (int it = 0; it < 4; ++it) {  // VT[d][t] from registers (LDS scatter)
    const int i4 = tid + 256 * it;
    const int t = i4 >> 4, d0 = (i4 & 15) * 4;
#pragma unroll
    for (int j = 0; j < 4; ++j) sm[(d0 + j) * 72 + t] = f2bf(vreg[it][j]);
  }
  __syncthreads();

  unsigned short* vg = vt16 + (size_t)(bh * C_ + c) * (D_ * T_);
  for (int i8 = tid; i8 < D_ * 8; i8 += 256) {
    const int d = i8 >> 3, t0 = (i8 & 7) * 8;
    *reinterpret_cast<short8*>(&vg[d * T_ + t0]) =
        *reinterpret_cast<const short8*>(&sm[d * 72 + t0]);
  }
  if (tid < M_) {  // ksE[m]
    float s = 0.f;
#pragma unroll
    for (int t8 = 0; t8 < 8; ++t8) {
      const short8 h8 =
          *reinterpret_cast<const short8*>(&sm[9216 + tid * 72 + t8 * 8]);
#pragma unroll
      for (int j = 0; j < 8; ++j) s += bf2f((unsigned short)h8[j]);
    }
    ksc[(size_t)(bh * C_ + c) * M_ + tid] = s;
  }
  if (tid >= 128 && tid < 128 + D_) {  // Vsum[d]
    const int d = tid - 128;
    float s = 0.f;
#pragma unroll
    for (int t8 = 0; t8 < 8; ++t8) {
      const short8 h8 = *reinterpret_cast<const short8*>(&sm[d * 72 + t8 * 8]);
#pragma unroll
      for (int j = 0; j < 8; ++j) s += bf2f((unsigned short)h8[j]);
    }
    vsum[(size_t)(bh * C_ + c) * D_ + d] = s;
  }
  // KVE^T[d][m] = sum_t v[t,d]*kpE[t,m] (NT: A=VT rows d, B=KPT rows m)
  f32x4 acc2[2][4];
#pragma unroll
  for (int i = 0; i < 2; ++i)
#pragma unroll
    for (int j = 0; j < 4; ++j) acc2[i][j] = {0.f, 0.f, 0.f, 0.f};
#pragma unroll
  for (int kk = 0; kk < 2; ++kk) {
    short8 av[2], bv[4];
#pragma unroll
    for (int ti = 0; ti < 2; ++ti)
      av[ti] = *reinterpret_cast<const short8*>(
          &sm[(rblk + ti * 16 + l15) * 72 + kk * 32 + l16 * 8]);
#pragma unroll
    for (int tj = 0; tj < 4; ++tj)
      bv[tj] = *reinterpret_cast<const short8*>(
          &sm[9216 + (cblk + tj * 16 + l15) * 72 + kk * 32 + l16 * 8]);
#pragma unroll
    for (int ti = 0; ti < 2; ++ti)
#pragma unroll
      for (int tj = 0; tj < 4; ++tj)
        acc2[ti][tj] = __builtin_amdgcn_mfma_f32_16x16x32_bf16(
            av[ti], bv[tj], acc2[ti][tj], 0, 0, 0);
  }
  // repack KVST (aliases PL; PL dead since dash MFMA) -> vector store
#pragma unroll
  for (int ti = 0; ti < 2; ++ti)
#pragma unroll
    for (int j = 0; j < 4; ++j) {
      const int row = rblk + ti * 16 + l16 * 4 + j;  // d
#pragma unroll
      for (int tj = 0; tj < 4; ++tj) {
        const int col = cblk + tj * 16 + l15;  // m
        sm[18432 + row * 136 + col] = f2bf(acc2[ti][tj][j]);
      }
    }
  __syncthreads();
  unsigned short* ob = kvc16 + (size_t)(bh * C_ + c) * (M_ * D_);
  for (int i8 = tid; i8 < D_ * 16; i8 += 256) {
    const int d = i8 >> 4, m0 = (i8 & 15) * 8;
    *reinterpret_cast<short8*>(&ob[d * M_ + m0]) =
        *reinterpret_cast<const short8*>(&sm[18432 + d * 136 + m0]);
  }
#undef DASH_MFMA
}

// Exclusive prefix across chunks with exact eps terms (unchanged from R7).
__global__ __launch_bounds__(256) void prefix_kernel(
    const unsigned short* __restrict__ kvc16,
    unsigned short* __restrict__ kvp16, float* __restrict__ ksc,
    const float* __restrict__ blockmax, const float* __restrict__ vsum) {
  __shared__ float bm_s[C_];
  __shared__ float sc_s[C_];
  __shared__ float vs_s[2][C_];
  const int bid = blockIdx.x;  // B*H*32
  const int ej = bid & 31, bh = bid >> 5;
  if (threadIdx.x < C_) bm_s[threadIdx.x] = blockmax[bh * C_ + threadIdx.x];
  if (threadIdx.x >= 64 && threadIdx.x < 64 + 2 * C_) {
    const int t = threadIdx.x - 64;
    const int ld = t >> 5, cc = t & 31;
    vs_s[ld][cc] = vsum[(size_t)(bh * C_ + cc) * D_ + ej * 2 + ld];
  }
  __syncthreads();
  if (threadIdx.x < C_) {
    float km = -INFINITY;
#pragma unroll
    for (int cc = 0; cc < C_; ++cc) km = fmaxf(km, bm_s[cc]);
    sc_s[threadIdx.x] = expf(bm_s[threadIdx.x] - km);
  }
  __syncthreads();
  const int e = ej * 256 + threadIdx.x;
  const int dl = threadIdx.x >> 7;
  float vals[C_];
#pragma unroll
  for (int cc = 0; cc < C_; ++cc)
    vals[cc] = bf2f(kvc16[(size_t)(bh * C_ + cc) * (M_ * D_) + e]) * sc_s[cc] +
               REPS_ * vs_s[dl][cc];
  float run = 0.f;
#pragma unroll
  for (int cc = 0; cc < C_; ++cc) {
    const float t = vals[cc];
    vals[cc] = run;
    run += t;
  }
#pragma unroll
  for (int cc = 0; cc < C_; ++cc)
    kvp16[(size_t)(bh * C_ + cc) * (M_ * D_) + e] = f2bf(vals[cc]);
  if (ej == 0 && threadIdx.x < M_) {
    const int m = threadIdx.x;
    float ks[C_];
#pragma unroll
    for (int cc = 0; cc < C_; ++cc)
      ks[cc] = ksc[(size_t)(bh * C_ + cc) * M_ + m] * sc_s[cc] + KEPS_;
    float rs = 0.f;
#pragma unroll
    for (int cc = 0; cc < C_; ++cc) {
      const float t = ks[cc];
      ks[cc] = rs;
      rs += t;
    }
#pragma unroll
    for (int cc = 0; cc < C_; ++cc)
      ksc[(size_t)(bh * C_ + cc) * M_ + m] = ks[cc];
  }
}

// Intra-chunk MFMA (R7) + T14: all 12 PV B-fragments (kvp, V^T — each used
// once) prefetched into registers at kernel top, hiding HBM/L2 latency under
// staging + S MFMA. LDS 46KB -> 3 blocks/CU.
__global__ __launch_bounds__(256, 3) void intra_kernel(
    const unsigned short* __restrict__ qp16,
    const unsigned short* __restrict__ kp16,
    const unsigned short* __restrict__ vt16,
    const unsigned short* __restrict__ kvp16, const float* __restrict__ ksp,
    const float* __restrict__ blockmax, float* __restrict__ out) {
  __shared__ __align__(16) unsigned short qp_s[T_][136];
  __shared__ __align__(16) unsigned short kp_s[T_][136];
  __shared__ __align__(16) unsigned short S_s[T_][72];
  __shared__ float ksp_s[M_];
  __shared__ float denp_s[4][T_];
  __shared__ float den_s[T_];
  __shared__ float qsum_s[T_];
  __shared__ float bm_s[C_];

  const int bid = blockIdx.x;
  const int c = bid % C_, bh = bid / C_;
  const int b = bh >> 3, h = bh & 7;
  const int tid = threadIdx.x;
  const int w = tid >> 6, lane = tid & 63;
  const int l15 = lane & 15, l16 = lane >> 4;
  const int dblk = (w & 1) * 32;

  const unsigned short* qpt = qp16 + ((size_t)bh * L_ + c * T_) * M_;
  const unsigned short* kpt = kp16 + ((size_t)bh * L_ + c * T_) * M_;
  const unsigned short* kvt = kvp16 + (size_t)(bh * C_ + c) * (M_ * D_);
  const unsigned short* vg = vt16 + (size_t)(bh * C_ + c) * (D_ * T_);

  // ---- T14 prefetch: PV B-fragments (each used exactly once) --------------
  short8 vtr[2][2], kvr[4][2];
#pragma unroll
  for (int kk = 0; kk < 2; ++kk)
#pragma unroll
    for (int tj = 0; tj < 2; ++tj)
      vtr[kk][tj] = *reinterpret_cast<const short8*>(
          &vg[(dblk + tj * 16 + l15) * T_ + kk * 32 + l16 * 8]);
#pragma unroll
  for (int kk = 0; kk < 4; ++kk)
#pragma unroll
    for (int tj = 0; tj < 2; ++tj)
      kvr[kk][tj] = *reinterpret_cast<const short8*>(
          &kvt[(dblk + tj * 16 + l15) * M_ + kk * 32 + l16 * 8]);

  if (tid < C_) bm_s[tid] = blockmax[bh * C_ + tid];
  for (int i8 = tid; i8 < T_ * 16; i8 += 256) {
    const int r = i8 >> 4, m0 = (i8 & 15) * 8;
    *reinterpret_cast<short8*>(&qp_s[r][m0]) =
        *reinterpret_cast<const short8*>(&qpt[r * M_ + m0]);
    *reinterpret_cast<short8*>(&kp_s[r][m0]) =
        *reinterpret_cast<const short8*>(&kpt[r * M_ + m0]);
  }
  if (tid < M_) ksp_s[tid] = ksp[(size_t)(bh * C_ + c) * M_ + tid];
  __syncthreads();

  // qsum[t] via 4-lane groups (wave w owns rows w*16..+15)
  {
    const int row = w * 16 + (lane >> 2), mseg = (lane & 3) * 32;
    float p = 0.f;
#pragma unroll
    for (int u = 0; u < 4; ++u) {
      const short8 h8 =
          *reinterpret_cast<const short8*>(&qp_s[row][mseg + u * 8]);
#pragma unroll
      for (int j = 0; j < 8; ++j) p += bf2f((unsigned short)h8[j]);
    }
    p += __shfl_xor(p, 1, 64);
    p += __shfl_xor(p, 2, 64);
    if ((lane & 3) == 0) qsum_s[row] = p;
  }
  __syncthreads();

  float km = -INFINITY;
#pragma unroll
  for (int cc = 0; cc < C_; ++cc) km = fmaxf(km, bm_s[cc]);
  const float sc = expf(bm_s[c] - km);

  const int rblk = (w >> 1) * 32, cblk = (w & 1) * 32;
  f32x4 Sacc[2][2];
#pragma unroll
  for (int i = 0; i < 2; ++i)
#pragma unroll
    for (int j = 0; j < 2; ++j) Sacc[i][j] = {0.f, 0.f, 0.f, 0.f};

#pragma unroll
  for (int kk = 0; kk < 4; ++kk) {
    short8 af[2], bf[2];
#pragma unroll
    for (int ti = 0; ti < 2; ++ti)
      af[ti] = *reinterpret_cast<const short8*>(
          &qp_s[rblk + ti * 16 + l15][kk * 32 + l16 * 8]);
#pragma unroll
    for (int tj = 0; tj < 2; ++tj)
      bf[tj] = *reinterpret_cast<const short8*>(
          &kp_s[cblk + tj * 16 + l15][kk * 32 + l16 * 8]);
#pragma unroll
    for (int ti = 0; ti < 2; ++ti)
#pragma unroll
      for (int tj = 0; tj < 2; ++tj)
        Sacc[ti][tj] = __builtin_amdgcn_mfma_f32_16x16x32_bf16(
            af[ti], bf[tj], Sacc[ti][tj], 0, 0, 0);
  }
#pragma unroll
  for (int ti = 0; ti < 2; ++ti)
#pragma unroll
    for (int tj = 0; tj < 2; ++tj)
#pragma unroll
      for (int j = 0; j < 4; ++j) {
        const int row = rblk + ti * 16 + l16 * 4 + j;
        const int col = cblk + tj * 16 + l15;
        const float add = REPS_ * qsum_s[row];
        const float sv = (col <= row) ? Sacc[ti][tj][j] * sc + add : 0.f;
        S_s[row][col] = f2bf(sv);
      }
  __syncthreads();

  {
    const int t = lane;
    float p = 0.f;
    if (w == 0) {
      for (int tp = 0; tp < 32; ++tp) p += bf2f(S_s[t][tp]);
    } else if (w == 1) {
      for (int tp = 32; tp < 64; ++tp) p += bf2f(S_s[t][tp]);
    } else if (w == 2) {
      for (int m = 0; m < 64; ++m) p += bf2f(qp_s[t][m]) * ksp_s[m];
    } else {
      for (int m = 64; m < 128; ++m) p += bf2f(qp_s[t][m]) * ksp_s[m];
    }
    denp_s[w][t] = p;
  }
  __syncthreads();
  if (tid < T_)
    den_s[tid] =
        denp_s[0][tid] + denp_s[1][tid] + denp_s[2][tid] + denp_s[3][tid];
  __syncthreads();

  f32x4 Nacc[2][2];
#pragma unroll
  for (int i = 0; i < 2; ++i)
#pragma unroll
    for (int j = 0; j < 2; ++j) Nacc[i][j] = {0.f, 0.f, 0.f, 0.f};

#pragma unroll
  for (int kk = 0; kk < 2; ++kk) {  // S @ V^T (V frags prefetched)
    short8 af[2];
#pragma unroll
    for (int ti = 0; ti < 2; ++ti)
      af[ti] = *reinterpret_cast<const short8*>(
          &S_s[rblk + ti * 16 + l15][kk * 32 + l16 * 8]);
#pragma unroll
    for (int ti = 0; ti < 2; ++ti)
#pragma unroll
      for (int tj = 0; tj < 2; ++tj)
        Nacc[ti][tj] = __builtin_amdgcn_mfma_f32_16x16x32_bf16(
            af[ti], vtr[kk][tj], Nacc[ti][tj], 0, 0, 0);
  }
#pragma unroll
  for (int kk = 0; kk < 4; ++kk) {  // qp @ KVp^T (KV frags prefetched)
    short8 af[2];
#pragma unroll
    for (int ti = 0; ti < 2; ++ti)
      af[ti] = *reinterpret_cast<const short8*>(
          &qp_s[rblk + ti * 16 + l15][kk * 32 + l16 * 8]);
#pragma unroll
    for (int ti = 0; ti < 2; ++ti)
#pragma unroll
      for (int tj = 0; tj < 2; ++tj)
        Nacc[ti][tj] = __builtin_amdgcn_mfma_f32_16x16x32_bf16(
            af[ti], kvr[kk][tj], Nacc[ti][tj], 0, 0, 0);
  }

#pragma unroll
  for (int ti = 0; ti < 2; ++ti)
#pragma unroll
    for (int j = 0; j < 4; ++j) {
      const int row = rblk + ti * 16 + l16 * 4 + j;
      const float r = 1.f / den_s[row];
      float* orow = out + ((size_t)(b * L_ + c * T_ + row) * H_ + h) * D_;
#pragma unroll
      for (int tj = 0; tj < 2; ++tj) {
        const int col = dblk + tj * 16 + l15;
        orow[col] = Nacc[ti][tj][j] * r;
      }
    }
}

extern "C" void kernel_launch(void* const* d_in, const int* in_sizes, int n_in,
                              void* d_out, int out_size, void* d_ws,
                              size_t ws_size, hipStream_t stream) {
  const float* q = (const float*)d_in[0];
  const float* k = (const float*)d_in[1];
  const float* v = (const float*)d_in[2];
  const float* P = (const float*)d_in[3];
  float* out = (float*)d_out;

  float* ws = (float*)d_ws;
  float* blockmax = ws;                                   // 512
  float* ksp = blockmax + 512;                            // B*H*C*M
  float* vsum = ksp + (size_t)B_ * H_ * C_ * M_;          // B*H*C*D
  unsigned short* qp16 = (unsigned short*)(vsum + (size_t)B_ * H_ * C_ * D_);
  unsigned short* kp16 = qp16 + (size_t)B_ * H_ * L_ * M_;
  unsigned short* kvc16 = kp16 + (size_t)B_ * H_ * L_ * M_;
  unsigned short* kvp16 = kvc16 + (size_t)B_ * H_ * C_ * D_ * M_;
  unsigned short* vt16 = kvp16 + (size_t)B_ * H_ * C_ * D_ * M_;

  feat_kernel<<<B_ * H_ * C_, 256, 0, stream>>>(q, k, P, v, qp16, kp16, kvc16,
                                                ksp, vt16, blockmax, vsum);
  prefix_kernel<<<B_ * H_ * 32, 256, 0, stream>>>(kvc16, kvp16, ksp, blockmax,
                                                  vsum);
  intra_kernel<<<B_ * H_ * C_, 256, 0, stream>>>(qp16, kp16, vt16, kvp16, ksp,
                                                 blockmax, out);
}

// Round 14
// 43.762 us; speedup vs baseline: 5.3505x; 1.0167x over previous
//
#include <hip/hip_runtime.h>
#include <math.h>

typedef __attribute__((ext_vector_type(8))) short short8;
typedef __attribute__((ext_vector_type(4))) float f32x4;
typedef __attribute__((ext_vector_type(4))) unsigned short u16x4;

// Problem constants: B=2, L=2048, H=8, D=64, M=128.
constexpr int B_ = 2, L_ = 2048, H_ = 8, D_ = 64, M_ = 128;
constexpr int T_ = 64;            // chunk length
constexpr int C_ = L_ / T_;       // 32 chunks
constexpr float DN_ = 0.35355339059327373f;     // 64^-0.25
constexpr float RATIO_ = 0.08838834764831845f;  // 1/sqrt(128)
constexpr float EPSV_ = 1e-6f;
constexpr float REPS_ = RATIO_ * EPSV_;   // ratio*eps: k' additive floor
constexpr float KEPS_ = 64.0f * REPS_;    // per-chunk ks eps mass

// feat LDS layout (short offsets), 73728 B static:
// XQH[64][72]@0, XQL@4608, XKH@9216, XKL@13824, PH[128][72]@18432, PL@27648.
// Aliases (all after their home's last read): QPST[64][136]@0 (over XQH+XQL),
// VT[64][72]@9216 (over XKH), KPT[128][72]@18432 (over PH),
// KVST[64][136]@27648 (over PL).
constexpr int XQH_ = 0, XQL_ = 4608, XKH_ = 9216, XKL_ = 13824;
constexpr int PHO_ = 18432, PLO_ = 27648;
constexpr int QPST_ = 0, VTO_ = 9216, KPTO_ = 18432, KVSTO_ = 27648;

__device__ inline unsigned short f2bf(float x) {  // RNE float->bf16
  const unsigned u = __float_as_uint(x);
  return (unsigned short)((u + 0x7fffu + ((u >> 16) & 1u)) >> 16);
}
__device__ inline float bf2f(unsigned short h) {
  return __uint_as_float(((unsigned)h) << 16);
}

// Fused feature kernel, grid 512 = (bh, chunk). R13 + flattened phases:
// q, k, P staged to LDS and v to registers ALL AT KERNEL TOP (one staging
// pass, max MLP, no K restage); then Q-dash MFMA -> {K-dash MFMA || Q
// epilogue} -> K epilogue -> KV MFMA. 5 barriers (was 7).
__global__ __launch_bounds__(256, 2) void feat_kernel(
    const float* __restrict__ q, const float* __restrict__ k,
    const float* __restrict__ P, const float* __restrict__ v,
    unsigned short* __restrict__ qp16, unsigned short* __restrict__ kp16,
    unsigned short* __restrict__ kvc16, float* __restrict__ ksc,
    unsigned short* __restrict__ vt16, float* __restrict__ blockmax,
    float* __restrict__ vsum) {
  __shared__ __align__(16) unsigned short sm[36864];  // 73.7 KB
  __shared__ float diagq_s[T_];
  __shared__ float diagk_s[T_];
  __shared__ float wred_s[2][T_];
  __shared__ float red4_s[4];

  const int sub = blockIdx.x;
  const int c = sub % C_, bh = sub / C_;
  const int b = bh >> 3, h = bh & 7;
  const int tid = threadIdx.x;
  const int w = tid >> 6, lane = tid & 63;
  const int l15 = lane & 15, l16 = lane >> 4;
  const int rblk = (w >> 1) * 32, cblk = (w & 1) * 64;

  // ---- V tile -> registers (T14; its LDS home is busy until sync3) --------
  f32x4 vreg[4];
#pragma unroll
  for (int it = 0; it < 4; ++it) {
    const int i4 = tid + 256 * it;
    const int r = i4 >> 4, d0 = (i4 & 15) * 4;
    vreg[it] = *reinterpret_cast<const f32x4*>(
        &v[((size_t)(b * L_ + c * T_ + r) * H_ + h) * D_ + d0]);
  }

#define STAGE_X(xptr, XB, LB, dg)                                             \
  _Pragma("unroll") for (int it = 0; it < 4; ++it) {                          \
    const int i4 = tid + 256 * it;                                            \
    const int r = i4 >> 4, d0 = (i4 & 15) * 4;                                \
    f32x4 t4 = *reinterpret_cast<const f32x4*>(                               \
        &(xptr)[((size_t)(b * L_ + c * T_ + r) * H_ + h) * D_ + d0]);         \
    u16x4 hi, lo;                                                             \
    float sq = 0.f;                                                           \
    _Pragma("unroll") for (int j = 0; j < 4; ++j) {                           \
      const float xv = t4[j] * DN_;                                           \
      sq += xv * xv;                                                          \
      const unsigned short hb = f2bf(xv);                                     \
      hi[j] = hb;                                                             \
      lo[j] = f2bf(xv - bf2f(hb));                                            \
    }                                                                         \
    *reinterpret_cast<u16x4*>(&sm[(XB) + r * 72 + d0]) = hi;                  \
    *reinterpret_cast<u16x4*>(&sm[(LB) + r * 72 + d0]) = lo;                  \
    _Pragma("unroll") for (int off = 1; off < 16; off <<= 1)                  \
        sq += __shfl_xor(sq, off, 64);                                        \
    if ((tid & 15) == 0) (dg)[r] = sq;                                        \
  }

#define DASH_MFMA(accv, XB, LB)                                               \
  _Pragma("unroll") for (int kk = 0; kk < 2; ++kk) {                          \
    short8 ah[2], al[2], bh8[4], bl8[4];                                      \
    _Pragma("unroll") for (int ti = 0; ti < 2; ++ti) {                        \
      ah[ti] = *reinterpret_cast<const short8*>(                              \
          &sm[(XB) + (rblk + ti * 16 + l15) * 72 + kk * 32 + l16 * 8]);       \
      al[ti] = *reinterpret_cast<const short8*>(                              \
          &sm[(LB) + (rblk + ti * 16 + l15) * 72 + kk * 32 + l16 * 8]);       \
    }                                                                         \
    _Pragma("unroll") for (int tj = 0; tj < 4; ++tj) {                        \
      bh8[tj] = *reinterpret_cast<const short8*>(                             \
          &sm[PHO_ + (cblk + tj * 16 + l15) * 72 + kk * 32 + l16 * 8]);       \
      bl8[tj] = *reinterpret_cast<const short8*>(                             \
          &sm[PLO_ + (cblk + tj * 16 + l15) * 72 + kk * 32 + l16 * 8]);       \
    }                                                                         \
    _Pragma("unroll") for (int ti = 0; ti < 2; ++ti)                          \
        _Pragma("unroll") for (int tj = 0; tj < 4; ++tj) {                    \
      accv[ti][tj] = __builtin_amdgcn_mfma_f32_16x16x32_bf16(                 \
          al[ti], bh8[tj], accv[ti][tj], 0, 0, 0);                            \
      accv[ti][tj] = __builtin_amdgcn_mfma_f32_16x16x32_bf16(                 \
          ah[ti], bl8[tj], accv[ti][tj], 0, 0, 0);                            \
      accv[ti][tj] = __builtin_amdgcn_mfma_f32_16x16x32_bf16(                 \
          ah[ti], bh8[tj], accv[ti][tj], 0, 0, 0);                            \
    }                                                                         \
  }

  // ---- Single staging pass: Xq, Xk, P (hi/lo splits) ----------------------
  STAGE_X(q, XQH_, XQL_, diagq_s);
  STAGE_X(k, XKH_, XKL_, diagk_s);
  for (int i4 = tid; i4 < M_ * 16; i4 += 256) {
    const int m = i4 >> 4, d0 = (i4 & 15) * 4;
    const f32x4 t4 = *reinterpret_cast<const f32x4*>(&P[m * D_ + d0]);
    u16x4 hi, lo;
#pragma unroll
    for (int j = 0; j < 4; ++j) {
      hi[j] = f2bf(t4[j]);
      lo[j] = f2bf(t4[j] - bf2f(hi[j]));
    }
    *reinterpret_cast<u16x4*>(&sm[PHO_ + m * 72 + d0]) = hi;
    *reinterpret_cast<u16x4*>(&sm[PLO_ + m * 72 + d0]) = lo;
  }
  __syncthreads();  // s1: all staging visible

  // ---- Q dash MFMA --------------------------------------------------------
  f32x4 accq[2][4];
#pragma unroll
  for (int i = 0; i < 2; ++i)
#pragma unroll
    for (int j = 0; j < 4; ++j) accq[i][j] = {0.f, 0.f, 0.f, 0.f};
  DASH_MFMA(accq, XQH_, XQL_);

  {  // Q per-row max over m
    float rmax[2][4];
#pragma unroll
    for (int ti = 0; ti < 2; ++ti)
#pragma unroll
      for (int j = 0; j < 4; ++j) {
        float m0 = fmaxf(fmaxf(accq[ti][0][j], accq[ti][1][j]),
                         fmaxf(accq[ti][2][j], accq[ti][3][j]));
#pragma unroll
        for (int off = 1; off < 16; off <<= 1)
          m0 = fmaxf(m0, __shfl_xor(m0, off, 64));
        rmax[ti][j] = m0;
      }
    if (l15 == 0) {
#pragma unroll
      for (int ti = 0; ti < 2; ++ti)
#pragma unroll
        for (int j = 0; j < 4; ++j)
          wred_s[w & 1][rblk + ti * 16 + l16 * 4 + j] = rmax[ti][j];
    }
  }
  __syncthreads();  // s2: wred visible; Q-MFMA reads of XQH/XQL done

  // ---- K dash MFMA (reads XKH/XKL/PH/PL — disjoint from QPST region) ------
  f32x4 acck[2][4];
#pragma unroll
  for (int i = 0; i < 2; ++i)
#pragma unroll
    for (int j = 0; j < 4; ++j) acck[i][j] = {0.f, 0.f, 0.f, 0.f};
  DASH_MFMA(acck, XKH_, XKL_);
  {
    float bm = -INFINITY;
#pragma unroll
    for (int ti = 0; ti < 2; ++ti)
#pragma unroll
      for (int tj = 0; tj < 4; ++tj)
#pragma unroll
        for (int j = 0; j < 4; ++j) bm = fmaxf(bm, acck[ti][tj][j]);
#pragma unroll
    for (int off = 1; off < 64; off <<= 1)
      bm = fmaxf(bm, __shfl_xor(bm, off, 64));
    if (lane == 0) red4_s[w] = bm;
  }
  // ---- Q epilogue (overlaps K MFMA in schedule): qp -> QPST ---------------
#pragma unroll
  for (int ti = 0; ti < 2; ++ti)
#pragma unroll
    for (int j = 0; j < 4; ++j) {
      const int row = rblk + ti * 16 + l16 * 4 + j;
      const float sub2 =
          0.5f * diagq_s[row] + fmaxf(wred_s[0][row], wred_s[1][row]);
#pragma unroll
      for (int tj = 0; tj < 4; ++tj) {
        const int col = cblk + tj * 16 + l15;
        sm[QPST_ + row * 136 + col] =
            f2bf(RATIO_ * (expf(accq[ti][tj][j] - sub2) + EPSV_));
      }
    }
  __syncthreads();  // s3: QPST + red4 visible; K-MFMA reads of XKH/PH/PL done

  // qp16 global write
  {
    unsigned short* outr = qp16 + ((size_t)bh * L_ + c * T_) * M_;
    for (int i8 = tid; i8 < T_ * 16; i8 += 256) {
      const int row = i8 >> 4, m0 = (i8 & 15) * 8;
      *reinterpret_cast<short8*>(&outr[row * M_ + m0]) =
          *reinterpret_cast<const short8*>(&sm[QPST_ + row * 136 + m0]);
    }
  }
  const float lmax =
      fmaxf(fmaxf(red4_s[0], red4_s[1]), fmaxf(red4_s[2], red4_s[3]));
  if (tid == 0) blockmax[sub] = lmax;

  // K epilogue: kpE (NO eps) -> global + KPT (over PH); VT from vreg (over XKH)
  {
    unsigned short* kpr = kp16 + ((size_t)bh * L_ + c * T_) * M_;
#pragma unroll
    for (int ti = 0; ti < 2; ++ti)
#pragma unroll
      for (int j = 0; j < 4; ++j) {
        const int row = rblk + ti * 16 + l16 * 4 + j;
        const float sub2 = 0.5f * diagk_s[row] + lmax;
#pragma unroll
        for (int tj = 0; tj < 4; ++tj) {
          const int col = cblk + tj * 16 + l15;
          const unsigned short us = f2bf(RATIO_ * expf(acck[ti][tj][j] - sub2));
          kpr[row * M_ + col] = us;
          sm[KPTO_ + col * 72 + row] = us;  // KPT[m][t]
        }
      }
  }
#pragma unroll
  for (int it = 0; it < 4; ++it) {  // VT[d][t] scatter from registers
    const int i4 = tid + 256 * it;
    const int t = i4 >> 4, d0 = (i4 & 15) * 4;
#pragma unroll
    for (int j = 0; j < 4; ++j) sm[VTO_ + (d0 + j) * 72 + t] = f2bf(vreg[it][j]);
  }
  __syncthreads();  // s4: KPT + VT visible

  {
    unsigned short* vg = vt16 + (size_t)(bh * C_ + c) * (D_ * T_);
    for (int i8 = tid; i8 < D_ * 8; i8 += 256) {
      const int d = i8 >> 3, t0 = (i8 & 7) * 8;
      *reinterpret_cast<short8*>(&vg[d * T_ + t0]) =
          *reinterpret_cast<const short8*>(&sm[VTO_ + d * 72 + t0]);
    }
  }
  if (tid < M_) {  // ksE[m]
    float s = 0.f;
#pragma unroll
    for (int t8 = 0; t8 < 8; ++t8) {
      const short8 h8 =
          *reinterpret_cast<const short8*>(&sm[KPTO_ + tid * 72 + t8 * 8]);
#pragma unroll
      for (int j = 0; j < 8; ++j) s += bf2f((unsigned short)h8[j]);
    }
    ksc[(size_t)(bh * C_ + c) * M_ + tid] = s;
  }
  if (tid >= 128 && tid < 128 + D_) {  // Vsum[d]
    const int d = tid - 128;
    float s = 0.f;
#pragma unroll
    for (int t8 = 0; t8 < 8; ++t8) {
      const short8 h8 =
          *reinterpret_cast<const short8*>(&sm[VTO_ + d * 72 + t8 * 8]);
#pragma unroll
      for (int j = 0; j < 8; ++j) s += bf2f((unsigned short)h8[j]);
    }
    vsum[(size_t)(bh * C_ + c) * D_ + d] = s;
  }
  // KV MFMA: KVE^T[d][m] = sum_t v[t,d]*kpE[t,m]  (A=VT, B=KPT)
  f32x4 acc2[2][4];
#pragma unroll
  for (int i = 0; i < 2; ++i)
#pragma unroll
    for (int j = 0; j < 4; ++j) acc2[i][j] = {0.f, 0.f, 0.f, 0.f};
#pragma unroll
  for (int kk = 0; kk < 2; ++kk) {
    short8 av[2], bv[4];
#pragma unroll
    for (int ti = 0; ti < 2; ++ti)
      av[ti] = *reinterpret_cast<const short8*>(
          &sm[VTO_ + (rblk + ti * 16 + l15) * 72 + kk * 32 + l16 * 8]);
#pragma unroll
    for (int tj = 0; tj < 4; ++tj)
      bv[tj] = *reinterpret_cast<const short8*>(
          &sm[KPTO_ + (cblk + tj * 16 + l15) * 72 + kk * 32 + l16 * 8]);
#pragma unroll
    for (int ti = 0; ti < 2; ++ti)
#pragma unroll
      for (int tj = 0; tj < 4; ++tj)
        acc2[ti][tj] = __builtin_amdgcn_mfma_f32_16x16x32_bf16(
            av[ti], bv[tj], acc2[ti][tj], 0, 0, 0);
  }
  // repack KVST (over PL; PL's last read was K dash, done at s3)
#pragma unroll
  for (int ti = 0; ti < 2; ++ti)
#pragma unroll
    for (int j = 0; j < 4; ++j) {
      const int row = rblk + ti * 16 + l16 * 4 + j;  // d
#pragma unroll
      for (int tj = 0; tj < 4; ++tj) {
        const int col = cblk + tj * 16 + l15;  // m
        sm[KVSTO_ + row * 136 + col] = f2bf(acc2[ti][tj][j]);
      }
    }
  __syncthreads();  // s5: KVST visible
  {
    unsigned short* ob = kvc16 + (size_t)(bh * C_ + c) * (M_ * D_);
    for (int i8 = tid; i8 < D_ * 16; i8 += 256) {
      const int d = i8 >> 4, m0 = (i8 & 15) * 8;
      *reinterpret_cast<short8*>(&ob[d * M_ + m0]) =
          *reinterpret_cast<const short8*>(&sm[KVSTO_ + d * 136 + m0]);
    }
  }
#undef STAGE_X
#undef DASH_MFMA
}

// Exclusive prefix across chunks with exact eps terms (unchanged).
__global__ __launch_bounds__(256) void prefix_kernel(
    const unsigned short* __restrict__ kvc16,
    unsigned short* __restrict__ kvp16, float* __restrict__ ksc,
    const float* __restrict__ blockmax, const float* __restrict__ vsum) {
  __shared__ float bm_s[C_];
  __shared__ float sc_s[C_];
  __shared__ float vs_s[2][C_];
  const int bid = blockIdx.x;  // B*H*32
  const int ej = bid & 31, bh = bid >> 5;
  if (threadIdx.x < C_) bm_s[threadIdx.x] = blockmax[bh * C_ + threadIdx.x];
  if (threadIdx.x >= 64 && threadIdx.x < 64 + 2 * C_) {
    const int t = threadIdx.x - 64;
    const int ld = t >> 5, cc = t & 31;
    vs_s[ld][cc] = vsum[(size_t)(bh * C_ + cc) * D_ + ej * 2 + ld];
  }
  __syncthreads();
  if (threadIdx.x < C_) {
    float km = -INFINITY;
#pragma unroll
    for (int cc = 0; cc < C_; ++cc) km = fmaxf(km, bm_s[cc]);
    sc_s[threadIdx.x] = expf(bm_s[threadIdx.x] - km);
  }
  __syncthreads();
  const int e = ej * 256 + threadIdx.x;
  const int dl = threadIdx.x >> 7;
  float vals[C_];
#pragma unroll
  for (int cc = 0; cc < C_; ++cc)
    vals[cc] = bf2f(kvc16[(size_t)(bh * C_ + cc) * (M_ * D_) + e]) * sc_s[cc] +
               REPS_ * vs_s[dl][cc];
  float run = 0.f;
#pragma unroll
  for (int cc = 0; cc < C_; ++cc) {
    const float t = vals[cc];
    vals[cc] = run;
    run += t;
  }
#pragma unroll
  for (int cc = 0; cc < C_; ++cc)
    kvp16[(size_t)(bh * C_ + cc) * (M_ * D_) + e] = f2bf(vals[cc]);
  if (ej == 0 && threadIdx.x < M_) {
    const int m = threadIdx.x;
    float ks[C_];
#pragma unroll
    for (int cc = 0; cc < C_; ++cc)
      ks[cc] = ksc[(size_t)(bh * C_ + cc) * M_ + m] * sc_s[cc] + KEPS_;
    float rs = 0.f;
#pragma unroll
    for (int cc = 0; cc < C_; ++cc) {
      const float t = ks[cc];
      ks[cc] = rs;
      rs += t;
    }
#pragma unroll
    for (int cc = 0; cc < C_; ++cc)
      ksc[(size_t)(bh * C_ + cc) * M_ + m] = ks[cc];
  }
}

// Intra-chunk MFMA + T14 prefetch of once-used PV B-fragments (unchanged).
__global__ __launch_bounds__(256, 3) void intra_kernel(
    const unsigned short* __restrict__ qp16,
    const unsigned short* __restrict__ kp16,
    const unsigned short* __restrict__ vt16,
    const unsigned short* __restrict__ kvp16, const float* __restrict__ ksp,
    const float* __restrict__ blockmax, float* __restrict__ out) {
  __shared__ __align__(16) unsigned short qp_s[T_][136];
  __shared__ __align__(16) unsigned short kp_s[T_][136];
  __shared__ __align__(16) unsigned short S_s[T_][72];
  __shared__ float ksp_s[M_];
  __shared__ float denp_s[4][T_];
  __shared__ float den_s[T_];
  __shared__ float qsum_s[T_];
  __shared__ float bm_s[C_];

  const int bid = blockIdx.x;
  const int c = bid % C_, bh = bid / C_;
  const int b = bh >> 3, h = bh & 7;
  const int tid = threadIdx.x;
  const int w = tid >> 6, lane = tid & 63;
  const int l15 = lane & 15, l16 = lane >> 4;
  const int dblk = (w & 1) * 32;

  const unsigned short* qpt = qp16 + ((size_t)bh * L_ + c * T_) * M_;
  const unsigned short* kpt = kp16 + ((size_t)bh * L_ + c * T_) * M_;
  const unsigned short* kvt = kvp16 + (size_t)(bh * C_ + c) * (M_ * D_);
  const unsigned short* vg = vt16 + (size_t)(bh * C_ + c) * (D_ * T_);

  short8 vtr[2][2], kvr[4][2];
#pragma unroll
  for (int kk = 0; kk < 2; ++kk)
#pragma unroll
    for (int tj = 0; tj < 2; ++tj)
      vtr[kk][tj] = *reinterpret_cast<const short8*>(
          &vg[(dblk + tj * 16 + l15) * T_ + kk * 32 + l16 * 8]);
#pragma unroll
  for (int kk = 0; kk < 4; ++kk)
#pragma unroll
    for (int tj = 0; tj < 2; ++tj)
      kvr[kk][tj] = *reinterpret_cast<const short8*>(
          &kvt[(dblk + tj * 16 + l15) * M_ + kk * 32 + l16 * 8]);

  if (tid < C_) bm_s[tid] = blockmax[bh * C_ + tid];
  for (int i8 = tid; i8 < T_ * 16; i8 += 256) {
    const int r = i8 >> 4, m0 = (i8 & 15) * 8;
    *reinterpret_cast<short8*>(&qp_s[r][m0]) =
        *reinterpret_cast<const short8*>(&qpt[r * M_ + m0]);
    *reinterpret_cast<short8*>(&kp_s[r][m0]) =
        *reinterpret_cast<const short8*>(&kpt[r * M_ + m0]);
  }
  if (tid < M_) ksp_s[tid] = ksp[(size_t)(bh * C_ + c) * M_ + tid];
  __syncthreads();

  {
    const int row = w * 16 + (lane >> 2), mseg = (lane & 3) * 32;
    float p = 0.f;
#pragma unroll
    for (int u = 0; u < 4; ++u) {
      const short8 h8 =
          *reinterpret_cast<const short8*>(&qp_s[row][mseg + u * 8]);
#pragma unroll
      for (int j = 0; j < 8; ++j) p += bf2f((unsigned short)h8[j]);
    }
    p += __shfl_xor(p, 1, 64);
    p += __shfl_xor(p, 2, 64);
    if ((lane & 3) == 0) qsum_s[row] = p;
  }
  __syncthreads();

  float km = -INFINITY;
#pragma unroll
  for (int cc = 0; cc < C_; ++cc) km = fmaxf(km, bm_s[cc]);
  const float sc = expf(bm_s[c] - km);

  const int rblk = (w >> 1) * 32, cblk = (w & 1) * 32;
  f32x4 Sacc[2][2];
#pragma unroll
  for (int i = 0; i < 2; ++i)
#pragma unroll
    for (int j = 0; j < 2; ++j) Sacc[i][j] = {0.f, 0.f, 0.f, 0.f};

#pragma unroll
  for (int kk = 0; kk < 4; ++kk) {
    short8 af[2], bf[2];
#pragma unroll
    for (int ti = 0; ti < 2; ++ti)
      af[ti] = *reinterpret_cast<const short8*>(
          &qp_s[rblk + ti * 16 + l15][kk * 32 + l16 * 8]);
#pragma unroll
    for (int tj = 0; tj < 2; ++tj)
      bf[tj] = *reinterpret_cast<const short8*>(
          &kp_s[cblk + tj * 16 + l15][kk * 32 + l16 * 8]);
#pragma unroll
    for (int ti = 0; ti < 2; ++ti)
#pragma unroll
      for (int tj = 0; tj < 2; ++tj)
        Sacc[ti][tj] = __builtin_amdgcn_mfma_f32_16x16x32_bf16(
            af[ti], bf[tj], Sacc[ti][tj], 0, 0, 0);
  }
#pragma unroll
  for (int ti = 0; ti < 2; ++ti)
#pragma unroll
    for (int tj = 0; tj < 2; ++tj)
#pragma unroll
      for (int j = 0; j < 4; ++j) {
        const int row = rblk + ti * 16 + l16 * 4 + j;
        const int col = cblk + tj * 16 + l15;
        const float add = REPS_ * qsum_s[row];
        const float sv = (col <= row) ? Sacc[ti][tj][j] * sc + add : 0.f;
        S_s[row][col] = f2bf(sv);
      }
  __syncthreads();

  {
    const int t = lane;
    float p = 0.f;
    if (w == 0) {
      for (int tp = 0; tp < 32; ++tp) p += bf2f(S_s[t][tp]);
    } else if (w == 1) {
      for (int tp = 32; tp < 64; ++tp) p += bf2f(S_s[t][tp]);
    } else if (w == 2) {
      for (int m = 0; m < 64; ++m) p += bf2f(qp_s[t][m]) * ksp_s[m];
    } else {
      for (int m = 64; m < 128; ++m) p += bf2f(qp_s[t][m]) * ksp_s[m];
    }
    denp_s[w][t] = p;
  }
  __syncthreads();
  if (tid < T_)
    den_s[tid] =
        denp_s[0][tid] + denp_s[1][tid] + denp_s[2][tid] + denp_s[3][tid];
  __syncthreads();

  f32x4 Nacc[2][2];
#pragma unroll
  for (int i = 0; i < 2; ++i)
#pragma unroll
    for (int j = 0; j < 2; ++j) Nacc[i][j] = {0.f, 0.f, 0.f, 0.f};

#pragma unroll
  for (int kk = 0; kk < 2; ++kk) {  // S @ V^T (V frags prefetched)
    short8 af[2];
#pragma unroll
    for (int ti = 0; ti < 2; ++ti)
      af[ti] = *reinterpret_cast<const short8*>(
          &S_s[rblk + ti * 16 + l15][kk * 32 + l16 * 8]);
#pragma unroll
    for (int ti = 0; ti < 2; ++ti)
#pragma unroll
      for (int tj = 0; tj < 2; ++tj)
        Nacc[ti][tj] = __builtin_amdgcn_mfma_f32_16x16x32_bf16(
            af[ti], vtr[kk][tj], Nacc[ti][tj], 0, 0, 0);
  }
#pragma unroll
  for (int kk = 0; kk < 4; ++kk) {  // qp @ KVp^T (KV frags prefetched)
    short8 af[2];
#pragma unroll
    for (int ti = 0; ti < 2; ++ti)
      af[ti] = *reinterpret_cast<const short8*>(
          &qp_s[rblk + ti * 16 + l15][kk * 32 + l16 * 8]);
#pragma unroll
    for (int ti = 0; ti < 2; ++ti)
#pragma unroll
      for (int tj = 0; tj < 2; ++tj)
        Nacc[ti][tj] = __builtin_amdgcn_mfma_f32_16x16x32_bf16(
            af[ti], kvr[kk][tj], Nacc[ti][tj], 0, 0, 0);
  }

#pragma unroll
  for (int ti = 0; ti < 2; ++ti)
#pragma unroll
    for (int j = 0; j < 4; ++j) {
      const int row = rblk + ti * 16 + l16 * 4 + j;
      const float r = 1.f / den_s[row];
      float* orow = out + ((size_t)(b * L_ + c * T_ + row) * H_ + h) * D_;
#pragma unroll
      for (int tj = 0; tj < 2; ++tj) {
        const int col = dblk + tj * 16 + l15;
        orow[col] = Nacc[ti][tj][j] * r;
      }
    }
}

extern "C" void kernel_launch(void* const* d_in, const int* in_sizes, int n_in,
                              void* d_out, int out_size, void* d_ws,
                              size_t ws_size, hipStream_t stream) {
  const float* q = (const float*)d_in[0];
  const float* k = (const float*)d_in[1];
  const float* v = (const float*)d_in[2];
  const float* P = (const float*)d_in[3];
  float* out = (float*)d_out;

  float* ws = (float*)d_ws;
  float* blockmax = ws;                                   // 512
  float* ksp = blockmax + 512;                            // B*H*C*M
  float* vsum = ksp + (size_t)B_ * H_ * C_ * M_;          // B*H*C*D
  unsigned short* qp16 = (unsigned short*)(vsum + (size_t)B_ * H_ * C_ * D_);
  unsigned short* kp16 = qp16 + (size_t)B_ * H_ * L_ * M_;
  unsigned short* kvc16 = kp16 + (size_t)B_ * H_ * L_ * M_;
  unsigned short* kvp16 = kvc16 + (size_t)B_ * H_ * C_ * D_ * M_;
  unsigned short* vt16 = kvp16 + (size_t)B_ * H_ * C_ * D_ * M_;

  feat_kernel<<<B_ * H_ * C_, 256, 0, stream>>>(q, k, P, v, qp16, kp16, kvc16,
                                                ksp, vt16, blockmax, vsum);
  prefix_kernel<<<B_ * H_ * 32, 256, 0, stream>>>(kvc16, kvp16, ksp, blockmax,
                                                  vsum);
  intra_kernel<<<B_ * H_ * C_, 256, 0, stream>>>(qp16, kp16, vt16, kvp16, ksp,
                                                 blockmax, out);
}

// Round 15
// 41.609 us; speedup vs baseline: 5.6274x; 1.0517x over previous
//
#include <hip/hip_runtime.h>
#include <math.h>

typedef __attribute__((ext_vector_type(8))) short short8;
typedef __attribute__((ext_vector_type(4))) float f32x4;
typedef __attribute__((ext_vector_type(4))) unsigned short u16x4;

// Problem constants: B=2, L=2048, H=8, D=64, M=128.
constexpr int B_ = 2, L_ = 2048, H_ = 8, D_ = 64, M_ = 128;
constexpr int T_ = 64;            // chunk length
constexpr int C_ = L_ / T_;       // 32 chunks
constexpr float DN_ = 0.35355339059327373f;     // 64^-0.25
constexpr float RATIO_ = 0.08838834764831845f;  // 1/sqrt(128)
constexpr float EPSV_ = 1e-6f;
constexpr float REPS_ = RATIO_ * EPSV_;   // ratio*eps: k' additive floor
constexpr float KEPS_ = 64.0f * REPS_;    // per-chunk ks eps mass

// feat LDS (short offsets), 46.1 KB static -> 3 blocks/CU:
// XQ[64][72]@0, XK[64][72]@4608, PH[128][72]@9216, VT[64][72]@18432.
// Aliases: QPST[64][136]@0 (over XQ+XK, after dash MFMAs),
// KPT[128][72]@9216 (over PH), KVST[64][136]@0 (over QPST after qp16 store).
constexpr int XQ_ = 0, XK_ = 4608, PHO_ = 9216, VTO_ = 18432;
constexpr int QPST_ = 0, KPTO_ = 9216, KVSTO_ = 0;

__device__ inline unsigned short f2bf(float x) {  // RNE float->bf16
  const unsigned u = __float_as_uint(x);
  return (unsigned short)((u + 0x7fffu + ((u >> 16) & 1u)) >> 16);
}
__device__ inline float bf2f(unsigned short h) {
  return __uint_as_float(((unsigned)h) << 16);
}

// Fused feature kernel, grid 512 = (bh, chunk). Single-product bf16 dash
// (lo-correction terms dropped: spends ~0.5% of the 5x accuracy margin for
// half the staging VALU, 1/3 the dash MFMAs, and 46KB LDS -> 3 blocks/CU).
__global__ __launch_bounds__(256, 3) void feat_kernel(
    const float* __restrict__ q, const float* __restrict__ k,
    const float* __restrict__ P, const float* __restrict__ v,
    unsigned short* __restrict__ qp16, unsigned short* __restrict__ kp16,
    unsigned short* __restrict__ kvc16, float* __restrict__ ksc,
    unsigned short* __restrict__ vt16, float* __restrict__ blockmax,
    float* __restrict__ vsum) {
  __shared__ __align__(16) unsigned short sm[23040];  // 46.1 KB
  __shared__ float diagq_s[T_];
  __shared__ float diagk_s[T_];
  __shared__ float wred_s[2][T_];
  __shared__ float red4_s[4];

  const int sub = blockIdx.x;
  const int c = sub % C_, bh = sub / C_;
  const int b = bh >> 3, h = bh & 7;
  const int tid = threadIdx.x;
  const int w = tid >> 6, lane = tid & 63;
  const int l15 = lane & 15, l16 = lane >> 4;
  const int rblk = (w >> 1) * 32, cblk = (w & 1) * 64;

#define STAGE_X(xptr, XB, dg)                                                 \
  _Pragma("unroll") for (int it = 0; it < 4; ++it) {                          \
    const int i4 = tid + 256 * it;                                            \
    const int r = i4 >> 4, d0 = (i4 & 15) * 4;                                \
    f32x4 t4 = *reinterpret_cast<const f32x4*>(                               \
        &(xptr)[((size_t)(b * L_ + c * T_ + r) * H_ + h) * D_ + d0]);         \
    u16x4 hi;                                                                 \
    float sq = 0.f;                                                           \
    _Pragma("unroll") for (int j = 0; j < 4; ++j) {                           \
      const float xv = t4[j] * DN_;                                           \
      sq += xv * xv;                                                          \
      hi[j] = f2bf(xv);                                                       \
    }                                                                         \
    *reinterpret_cast<u16x4*>(&sm[(XB) + r * 72 + d0]) = hi;                  \
    _Pragma("unroll") for (int off = 1; off < 16; off <<= 1)                  \
        sq += __shfl_xor(sq, off, 64);                                        \
    if ((tid & 15) == 0) (dg)[r] = sq;                                        \
  }

#define DASH_MFMA(accv, XB)                                                   \
  _Pragma("unroll") for (int kk = 0; kk < 2; ++kk) {                          \
    short8 ah[2], bh8[4];                                                     \
    _Pragma("unroll") for (int ti = 0; ti < 2; ++ti)                          \
      ah[ti] = *reinterpret_cast<const short8*>(                              \
          &sm[(XB) + (rblk + ti * 16 + l15) * 72 + kk * 32 + l16 * 8]);       \
    _Pragma("unroll") for (int tj = 0; tj < 4; ++tj)                          \
      bh8[tj] = *reinterpret_cast<const short8*>(                             \
          &sm[PHO_ + (cblk + tj * 16 + l15) * 72 + kk * 32 + l16 * 8]);       \
    _Pragma("unroll") for (int ti = 0; ti < 2; ++ti)                          \
        _Pragma("unroll") for (int tj = 0; tj < 4; ++tj)                      \
            accv[ti][tj] = __builtin_amdgcn_mfma_f32_16x16x32_bf16(           \
                ah[ti], bh8[tj], accv[ti][tj], 0, 0, 0);                      \
  }

  // ---- Phase 1: stage Xq, Xk, P (bf16) and V^T (scatter) ------------------
  STAGE_X(q, XQ_, diagq_s);
  STAGE_X(k, XK_, diagk_s);
  for (int i4 = tid; i4 < M_ * 16; i4 += 256) {
    const int m = i4 >> 4, d0 = (i4 & 15) * 4;
    const f32x4 t4 = *reinterpret_cast<const f32x4*>(&P[m * D_ + d0]);
    u16x4 hi;
#pragma unroll
    for (int j = 0; j < 4; ++j) hi[j] = f2bf(t4[j]);
    *reinterpret_cast<u16x4*>(&sm[PHO_ + m * 72 + d0]) = hi;
  }
#pragma unroll
  for (int it = 0; it < 4; ++it) {  // V^T[d][t] directly (home free from start)
    const int i4 = tid + 256 * it;
    const int t = i4 >> 4, d0 = (i4 & 15) * 4;
    const f32x4 t4 = *reinterpret_cast<const f32x4*>(
        &v[((size_t)(b * L_ + c * T_ + t) * H_ + h) * D_ + d0]);
#pragma unroll
    for (int j = 0; j < 4; ++j) sm[VTO_ + (d0 + j) * 72 + t] = f2bf(t4[j]);
  }
  __syncthreads();  // s1

  // ---- Phase 2: Q dash + K dash MFMA + reductions -------------------------
  f32x4 accq[2][4], acck[2][4];
#pragma unroll
  for (int i = 0; i < 2; ++i)
#pragma unroll
    for (int j = 0; j < 4; ++j) {
      accq[i][j] = {0.f, 0.f, 0.f, 0.f};
      acck[i][j] = {0.f, 0.f, 0.f, 0.f};
    }
  DASH_MFMA(accq, XQ_);
  DASH_MFMA(acck, XK_);
  {  // Q per-row max
    float rmax[2][4];
#pragma unroll
    for (int ti = 0; ti < 2; ++ti)
#pragma unroll
      for (int j = 0; j < 4; ++j) {
        float m0 = fmaxf(fmaxf(accq[ti][0][j], accq[ti][1][j]),
                         fmaxf(accq[ti][2][j], accq[ti][3][j]));
#pragma unroll
        for (int off = 1; off < 16; off <<= 1)
          m0 = fmaxf(m0, __shfl_xor(m0, off, 64));
        rmax[ti][j] = m0;
      }
    if (l15 == 0) {
#pragma unroll
      for (int ti = 0; ti < 2; ++ti)
#pragma unroll
        for (int j = 0; j < 4; ++j)
          wred_s[w & 1][rblk + ti * 16 + l16 * 4 + j] = rmax[ti][j];
    }
  }
  {  // K chunk max
    float bm = -INFINITY;
#pragma unroll
    for (int ti = 0; ti < 2; ++ti)
#pragma unroll
      for (int tj = 0; tj < 4; ++tj)
#pragma unroll
        for (int j = 0; j < 4; ++j) bm = fmaxf(bm, acck[ti][tj][j]);
#pragma unroll
    for (int off = 1; off < 64; off <<= 1)
      bm = fmaxf(bm, __shfl_xor(bm, off, 64));
    if (lane == 0) red4_s[w] = bm;
  }
  __syncthreads();  // s2: wred/red4 visible; all dash reads of XQ/XK/PH done

  // ---- Phase 3: epilogues -------------------------------------------------
  const float lmax =
      fmaxf(fmaxf(red4_s[0], red4_s[1]), fmaxf(red4_s[2], red4_s[3]));
  if (tid == 0) blockmax[sub] = lmax;
#pragma unroll
  for (int ti = 0; ti < 2; ++ti)  // Q: qp (with +eps) -> QPST (over XQ+XK)
#pragma unroll
    for (int j = 0; j < 4; ++j) {
      const int row = rblk + ti * 16 + l16 * 4 + j;
      const float sub2 =
          0.5f * diagq_s[row] + fmaxf(wred_s[0][row], wred_s[1][row]);
#pragma unroll
      for (int tj = 0; tj < 4; ++tj) {
        const int col = cblk + tj * 16 + l15;
        sm[QPST_ + row * 136 + col] =
            f2bf(RATIO_ * (expf(accq[ti][tj][j] - sub2) + EPSV_));
      }
    }
  {  // K: kpE (NO eps) -> kp16 global + KPT (over PH)
    unsigned short* kpr = kp16 + ((size_t)bh * L_ + c * T_) * M_;
#pragma unroll
    for (int ti = 0; ti < 2; ++ti)
#pragma unroll
      for (int j = 0; j < 4; ++j) {
        const int row = rblk + ti * 16 + l16 * 4 + j;
        const float sub2 = 0.5f * diagk_s[row] + lmax;
#pragma unroll
        for (int tj = 0; tj < 4; ++tj) {
          const int col = cblk + tj * 16 + l15;
          const unsigned short us = f2bf(RATIO_ * expf(acck[ti][tj][j] - sub2));
          kpr[row * M_ + col] = us;
          sm[KPTO_ + col * 72 + row] = us;
        }
      }
  }
  __syncthreads();  // s3: QPST + KPT visible

  // ---- Phase 4: global stores + sums + KV MFMA ----------------------------
  {
    unsigned short* outr = qp16 + ((size_t)bh * L_ + c * T_) * M_;
    for (int i8 = tid; i8 < T_ * 16; i8 += 256) {
      const int row = i8 >> 4, m0 = (i8 & 15) * 8;
      *reinterpret_cast<short8*>(&outr[row * M_ + m0]) =
          *reinterpret_cast<const short8*>(&sm[QPST_ + row * 136 + m0]);
    }
    unsigned short* vg = vt16 + (size_t)(bh * C_ + c) * (D_ * T_);
    for (int i8 = tid; i8 < D_ * 8; i8 += 256) {
      const int d = i8 >> 3, t0 = (i8 & 7) * 8;
      *reinterpret_cast<short8*>(&vg[d * T_ + t0]) =
          *reinterpret_cast<const short8*>(&sm[VTO_ + d * 72 + t0]);
    }
  }
  if (tid < M_) {  // ksE[m]
    float s = 0.f;
#pragma unroll
    for (int t8 = 0; t8 < 8; ++t8) {
      const short8 h8 =
          *reinterpret_cast<const short8*>(&sm[KPTO_ + tid * 72 + t8 * 8]);
#pragma unroll
      for (int j = 0; j < 8; ++j) s += bf2f((unsigned short)h8[j]);
    }
    ksc[(size_t)(bh * C_ + c) * M_ + tid] = s;
  }
  if (tid >= 128 && tid < 128 + D_) {  // Vsum[d]
    const int d = tid - 128;
    float s = 0.f;
#pragma unroll
    for (int t8 = 0; t8 < 8; ++t8) {
      const short8 h8 =
          *reinterpret_cast<const short8*>(&sm[VTO_ + d * 72 + t8 * 8]);
#pragma unroll
      for (int j = 0; j < 8; ++j) s += bf2f((unsigned short)h8[j]);
    }
    vsum[(size_t)(bh * C_ + c) * D_ + d] = s;
  }
  // KV MFMA: KVE^T[d][m] = sum_t v[t,d]*kpE[t,m]  (A=VT, B=KPT)
  f32x4 acc2[2][4];
#pragma unroll
  for (int i = 0; i < 2; ++i)
#pragma unroll
    for (int j = 0; j < 4; ++j) acc2[i][j] = {0.f, 0.f, 0.f, 0.f};
#pragma unroll
  for (int kk = 0; kk < 2; ++kk) {
    short8 av[2], bv[4];
#pragma unroll
    for (int ti = 0; ti < 2; ++ti)
      av[ti] = *reinterpret_cast<const short8*>(
          &sm[VTO_ + (rblk + ti * 16 + l15) * 72 + kk * 32 + l16 * 8]);
#pragma unroll
    for (int tj = 0; tj < 4; ++tj)
      bv[tj] = *reinterpret_cast<const short8*>(
          &sm[KPTO_ + (cblk + tj * 16 + l15) * 72 + kk * 32 + l16 * 8]);
#pragma unroll
    for (int ti = 0; ti < 2; ++ti)
#pragma unroll
      for (int tj = 0; tj < 4; ++tj)
        acc2[ti][tj] = __builtin_amdgcn_mfma_f32_16x16x32_bf16(
            av[ti], bv[tj], acc2[ti][tj], 0, 0, 0);
  }
  __syncthreads();  // s4: QPST reads (qp16 store) done -> KVST may overwrite
#pragma unroll
  for (int ti = 0; ti < 2; ++ti)
#pragma unroll
    for (int j = 0; j < 4; ++j) {
      const int row = rblk + ti * 16 + l16 * 4 + j;  // d
#pragma unroll
      for (int tj = 0; tj < 4; ++tj) {
        const int col = cblk + tj * 16 + l15;  // m
        sm[KVSTO_ + row * 136 + col] = f2bf(acc2[ti][tj][j]);
      }
    }
  __syncthreads();  // s5: KVST visible
  {
    unsigned short* ob = kvc16 + (size_t)(bh * C_ + c) * (M_ * D_);
    for (int i8 = tid; i8 < D_ * 16; i8 += 256) {
      const int d = i8 >> 4, m0 = (i8 & 15) * 8;
      *reinterpret_cast<short8*>(&ob[d * M_ + m0]) =
          *reinterpret_cast<const short8*>(&sm[KVSTO_ + d * 136 + m0]);
    }
  }
#undef STAGE_X
#undef DASH_MFMA
}

// Exclusive prefix across chunks with exact eps terms (unchanged).
__global__ __launch_bounds__(256) void prefix_kernel(
    const unsigned short* __restrict__ kvc16,
    unsigned short* __restrict__ kvp16, float* __restrict__ ksc,
    const float* __restrict__ blockmax, const float* __restrict__ vsum) {
  __shared__ float bm_s[C_];
  __shared__ float sc_s[C_];
  __shared__ float vs_s[2][C_];
  const int bid = blockIdx.x;  // B*H*32
  const int ej = bid & 31, bh = bid >> 5;
  if (threadIdx.x < C_) bm_s[threadIdx.x] = blockmax[bh * C_ + threadIdx.x];
  if (threadIdx.x >= 64 && threadIdx.x < 64 + 2 * C_) {
    const int t = threadIdx.x - 64;
    const int ld = t >> 5, cc = t & 31;
    vs_s[ld][cc] = vsum[(size_t)(bh * C_ + cc) * D_ + ej * 2 + ld];
  }
  __syncthreads();
  if (threadIdx.x < C_) {
    float km = -INFINITY;
#pragma unroll
    for (int cc = 0; cc < C_; ++cc) km = fmaxf(km, bm_s[cc]);
    sc_s[threadIdx.x] = expf(bm_s[threadIdx.x] - km);
  }
  __syncthreads();
  const int e = ej * 256 + threadIdx.x;
  const int dl = threadIdx.x >> 7;
  float vals[C_];
#pragma unroll
  for (int cc = 0; cc < C_; ++cc)
    vals[cc] = bf2f(kvc16[(size_t)(bh * C_ + cc) * (M_ * D_) + e]) * sc_s[cc] +
               REPS_ * vs_s[dl][cc];
  float run = 0.f;
#pragma unroll
  for (int cc = 0; cc < C_; ++cc) {
    const float t = vals[cc];
    vals[cc] = run;
    run += t;
  }
#pragma unroll
  for (int cc = 0; cc < C_; ++cc)
    kvp16[(size_t)(bh * C_ + cc) * (M_ * D_) + e] = f2bf(vals[cc]);
  if (ej == 0 && threadIdx.x < M_) {
    const int m = threadIdx.x;
    float ks[C_];
#pragma unroll
    for (int cc = 0; cc < C_; ++cc)
      ks[cc] = ksc[(size_t)(bh * C_ + cc) * M_ + m] * sc_s[cc] + KEPS_;
    float rs = 0.f;
#pragma unroll
    for (int cc = 0; cc < C_; ++cc) {
      const float t = ks[cc];
      ks[cc] = rs;
      rs += t;
    }
#pragma unroll
    for (int cc = 0; cc < C_; ++cc)
      ksc[(size_t)(bh * C_ + cc) * M_ + m] = ks[cc];
  }
}

// Intra-chunk MFMA + T14 prefetch of once-used PV B-fragments (unchanged).
__global__ __launch_bounds__(256, 3) void intra_kernel(
    const unsigned short* __restrict__ qp16,
    const unsigned short* __restrict__ kp16,
    const unsigned short* __restrict__ vt16,
    const unsigned short* __restrict__ kvp16, const float* __restrict__ ksp,
    const float* __restrict__ blockmax, float* __restrict__ out) {
  __shared__ __align__(16) unsigned short qp_s[T_][136];
  __shared__ __align__(16) unsigned short kp_s[T_][136];
  __shared__ __align__(16) unsigned short S_s[T_][72];
  __shared__ float ksp_s[M_];
  __shared__ float denp_s[4][T_];
  __shared__ float den_s[T_];
  __shared__ float qsum_s[T_];
  __shared__ float bm_s[C_];

  const int bid = blockIdx.x;
  const int c = bid % C_, bh = bid / C_;
  const int b = bh >> 3, h = bh & 7;
  const int tid = threadIdx.x;
  const int w = tid >> 6, lane = tid & 63;
  const int l15 = lane & 15, l16 = lane >> 4;
  const int dblk = (w & 1) * 32;

  const unsigned short* qpt = qp16 + ((size_t)bh * L_ + c * T_) * M_;
  const unsigned short* kpt = kp16 + ((size_t)bh * L_ + c * T_) * M_;
  const unsigned short* kvt = kvp16 + (size_t)(bh * C_ + c) * (M_ * D_);
  const unsigned short* vg = vt16 + (size_t)(bh * C_ + c) * (D_ * T_);

  short8 vtr[2][2], kvr[4][2];
#pragma unroll
  for (int kk = 0; kk < 2; ++kk)
#pragma unroll
    for (int tj = 0; tj < 2; ++tj)
      vtr[kk][tj] = *reinterpret_cast<const short8*>(
          &vg[(dblk + tj * 16 + l15) * T_ + kk * 32 + l16 * 8]);
#pragma unroll
  for (int kk = 0; kk < 4; ++kk)
#pragma unroll
    for (int tj = 0; tj < 2; ++tj)
      kvr[kk][tj] = *reinterpret_cast<const short8*>(
          &kvt[(dblk + tj * 16 + l15) * M_ + kk * 32 + l16 * 8]);

  if (tid < C_) bm_s[tid] = blockmax[bh * C_ + tid];
  for (int i8 = tid; i8 < T_ * 16; i8 += 256) {
    const int r = i8 >> 4, m0 = (i8 & 15) * 8;
    *reinterpret_cast<short8*>(&qp_s[r][m0]) =
        *reinterpret_cast<const short8*>(&qpt[r * M_ + m0]);
    *reinterpret_cast<short8*>(&kp_s[r][m0]) =
        *reinterpret_cast<const short8*>(&kpt[r * M_ + m0]);
  }
  if (tid < M_) ksp_s[tid] = ksp[(size_t)(bh * C_ + c) * M_ + tid];
  __syncthreads();

  {
    const int row = w * 16 + (lane >> 2), mseg = (lane & 3) * 32;
    float p = 0.f;
#pragma unroll
    for (int u = 0; u < 4; ++u) {
      const short8 h8 =
          *reinterpret_cast<const short8*>(&qp_s[row][mseg + u * 8]);
#pragma unroll
      for (int j = 0; j < 8; ++j) p += bf2f((unsigned short)h8[j]);
    }
    p += __shfl_xor(p, 1, 64);
    p += __shfl_xor(p, 2, 64);
    if ((lane & 3) == 0) qsum_s[row] = p;
  }
  __syncthreads();

  float km = -INFINITY;
#pragma unroll
  for (int cc = 0; cc < C_; ++cc) km = fmaxf(km, bm_s[cc]);
  const float sc = expf(bm_s[c] - km);

  const int rblk = (w >> 1) * 32, cblk = (w & 1) * 32;
  f32x4 Sacc[2][2];
#pragma unroll
  for (int i = 0; i < 2; ++i)
#pragma unroll
    for (int j = 0; j < 2; ++j) Sacc[i][j] = {0.f, 0.f, 0.f, 0.f};

#pragma unroll
  for (int kk = 0; kk < 4; ++kk) {
    short8 af[2], bf[2];
#pragma unroll
    for (int ti = 0; ti < 2; ++ti)
      af[ti] = *reinterpret_cast<const short8*>(
          &qp_s[rblk + ti * 16 + l15][kk * 32 + l16 * 8]);
#pragma unroll
    for (int tj = 0; tj < 2; ++tj)
      bf[tj] = *reinterpret_cast<const short8*>(
          &kp_s[cblk + tj * 16 + l15][kk * 32 + l16 * 8]);
#pragma unroll
    for (int ti = 0; ti < 2; ++ti)
#pragma unroll
      for (int tj = 0; tj < 2; ++tj)
        Sacc[ti][tj] = __builtin_amdgcn_mfma_f32_16x16x32_bf16(
            af[ti], bf[tj], Sacc[ti][tj], 0, 0, 0);
  }
#pragma unroll
  for (int ti = 0; ti < 2; ++ti)
#pragma unroll
    for (int tj = 0; tj < 2; ++tj)
#pragma unroll
      for (int j = 0; j < 4; ++j) {
        const int row = rblk + ti * 16 + l16 * 4 + j;
        const int col = cblk + tj * 16 + l15;
        const float add = REPS_ * qsum_s[row];
        const float sv = (col <= row) ? Sacc[ti][tj][j] * sc + add : 0.f;
        S_s[row][col] = f2bf(sv);
      }
  __syncthreads();

  {
    const int t = lane;
    float p = 0.f;
    if (w == 0) {
      for (int tp = 0; tp < 32; ++tp) p += bf2f(S_s[t][tp]);
    } else if (w == 1) {
      for (int tp = 32; tp < 64; ++tp) p += bf2f(S_s[t][tp]);
    } else if (w == 2) {
      for (int m = 0; m < 64; ++m) p += bf2f(qp_s[t][m]) * ksp_s[m];
    } else {
      for (int m = 64; m < 128; ++m) p += bf2f(qp_s[t][m]) * ksp_s[m];
    }
    denp_s[w][t] = p;
  }
  __syncthreads();
  if (tid < T_)
    den_s[tid] =
        denp_s[0][tid] + denp_s[1][tid] + denp_s[2][tid] + denp_s[3][tid];
  __syncthreads();

  f32x4 Nacc[2][2];
#pragma unroll
  for (int i = 0; i < 2; ++i)
#pragma unroll
    for (int j = 0; j < 2; ++j) Nacc[i][j] = {0.f, 0.f, 0.f, 0.f};

#pragma unroll
  for (int kk = 0; kk < 2; ++kk) {  // S @ V^T (V frags prefetched)
    short8 af[2];
#pragma unroll
    for (int ti = 0; ti < 2; ++ti)
      af[ti] = *reinterpret_cast<const short8*>(
          &S_s[rblk + ti * 16 + l15][kk * 32 + l16 * 8]);
#pragma unroll
    for (int ti = 0; ti < 2; ++ti)
#pragma unroll
      for (int tj = 0; tj < 2; ++tj)
        Nacc[ti][tj] = __builtin_amdgcn_mfma_f32_16x16x32_bf16(
            af[ti], vtr[kk][tj], Nacc[ti][tj], 0, 0, 0);
  }
#pragma unroll
  for (int kk = 0; kk < 4; ++kk) {  // qp @ KVp^T (KV frags prefetched)
    short8 af[2];
#pragma unroll
    for (int ti = 0; ti < 2; ++ti)
      af[ti] = *reinterpret_cast<const short8*>(
          &qp_s[rblk + ti * 16 + l15][kk * 32 + l16 * 8]);
#pragma unroll
    for (int ti = 0; ti < 2; ++ti)
#pragma unroll
      for (int tj = 0; tj < 2; ++tj)
        Nacc[ti][tj] = __builtin_amdgcn_mfma_f32_16x16x32_bf16(
            af[ti], kvr[kk][tj], Nacc[ti][tj], 0, 0, 0);
  }

#pragma unroll
  for (int ti = 0; ti < 2; ++ti)
#pragma unroll
    for (int j = 0; j < 4; ++j) {
      const int row = rblk + ti * 16 + l16 * 4 + j;
      const float r = 1.f / den_s[row];
      float* orow = out + ((size_t)(b * L_ + c * T_ + row) * H_ + h) * D_;
#pragma unroll
      for (int tj = 0; tj < 2; ++tj) {
        const int col = dblk + tj * 16 + l15;
        orow[col] = Nacc[ti][tj][j] * r;
      }
    }
}

extern "C" void kernel_launch(void* const* d_in, const int* in_sizes, int n_in,
                              void* d_out, int out_size, void* d_ws,
                              size_t ws_size, hipStream_t stream) {
  const float* q = (const float*)d_in[0];
  const float* k = (const float*)d_in[1];
  const float* v = (const float*)d_in[2];
  const float* P = (const float*)d_in[3];
  float* out = (float*)d_out;

  float* ws = (float*)d_ws;
  float* blockmax = ws;                                   // 512
  float* ksp = blockmax + 512;                            // B*H*C*M
  float* vsum = ksp + (size_t)B_ * H_ * C_ * M_;          // B*H*C*D
  unsigned short* qp16 = (unsigned short*)(vsum + (size_t)B_ * H_ * C_ * D_);
  unsigned short* kp16 = qp16 + (size_t)B_ * H_ * L_ * M_;
  unsigned short* kvc16 = kp16 + (size_t)B_ * H_ * L_ * M_;
  unsigned short* kvp16 = kvc16 + (size_t)B_ * H_ * C_ * D_ * M_;
  unsigned short* vt16 = kvp16 + (size_t)B_ * H_ * C_ * D_ * M_;

  feat_kernel<<<B_ * H_ * C_, 256, 0, stream>>>(q, k, P, v, qp16, kp16, kvc16,
                                                ksp, vt16, blockmax, vsum);
  prefix_kernel<<<B_ * H_ * 32, 256, 0, stream>>>(kvc16, kvp16, ksp, blockmax,
                                                  vsum);
  intra_kernel<<<B_ * H_ * C_, 256, 0, stream>>>(qp16, kp16, vt16, kvp16, ksp,
                                                 blockmax, out);
}

// Round 16
// 41.275 us; speedup vs baseline: 5.6729x; 1.0081x over previous
//
#include <hip/hip_runtime.h>
#include <math.h>

typedef __attribute__((ext_vector_type(8))) short short8;
typedef __attribute__((ext_vector_type(4))) float f32x4;
typedef __attribute__((ext_vector_type(4))) unsigned short u16x4;

// Problem constants: B=2, L=2048, H=8, D=64, M=128.
constexpr int B_ = 2, L_ = 2048, H_ = 8, D_ = 64, M_ = 128;
constexpr int T_ = 64;            // chunk length
constexpr int C_ = L_ / T_;       // 32 chunks
constexpr float DN_ = 0.35355339059327373f;     // 64^-0.25
constexpr float RATIO_ = 0.08838834764831845f;  // 1/sqrt(128)
constexpr float EPSV_ = 1e-6f;
constexpr float REPS_ = RATIO_ * EPSV_;   // ratio*eps: k' additive floor
constexpr float KEPS_ = 64.0f * REPS_;    // per-chunk ks eps mass

__device__ inline unsigned short f2bf(float x) {  // RNE float->bf16
  const unsigned u = __float_as_uint(x);
  return (unsigned short)((u + 0x7fffu + ((u >> 16) & 1u)) >> 16);
}
__device__ inline float bf2f(unsigned short h) {
  return __uint_as_float(((unsigned)h) << 16);
}

// ---------------- feat: K-side only ----------------
// LDS (shorts, 18432 = 36.9KB -> 4 blocks/CU): XK[64][72]@0, PH[128][72]@4608,
// VT[64][72]@13824. Aliases: KPT[128][72]@4608 (over PH, after dash),
// KVST[64][136]@4608 (over KPT, after KV MFMA).
// qp16/kp16 globals are GONE (round-16): intra recomputes the feature maps
// from q/k/P (bit-identical: same bf16 staging + same blockmax units) —
// saves their 67MB of HBM round-trip.
constexpr int FXK_ = 0, FPH_ = 4608, FVT_ = 13824;
constexpr int FKPT_ = 4608, FKVST_ = 4608;

__global__ __launch_bounds__(256, 4) void feat_kernel(
    const float* __restrict__ k, const float* __restrict__ P,
    const float* __restrict__ v, unsigned short* __restrict__ kvc16,
    float* __restrict__ ksc, unsigned short* __restrict__ vt16,
    float* __restrict__ blockmax, float* __restrict__ vsum) {
  __shared__ __align__(16) unsigned short sm[18432];
  __shared__ float diagk_s[T_];
  __shared__ float red4_s[4];

  const int sub = blockIdx.x;
  const int c = sub % C_, bh = sub / C_;
  const int b = bh >> 3, h = bh & 7;
  const int tid = threadIdx.x;
  const int w = tid >> 6, lane = tid & 63;
  const int l15 = lane & 15, l16 = lane >> 4;
  const int rblk = (w >> 1) * 32, cblk = (w & 1) * 64;

  // ---- stage k (bf16 + diag), P (bf16), V^T (scatter) ----
#pragma unroll
  for (int it = 0; it < 4; ++it) {
    const int i4 = tid + 256 * it;
    const int r = i4 >> 4, d0 = (i4 & 15) * 4;
    f32x4 t4 = *reinterpret_cast<const f32x4*>(
        &k[((size_t)(b * L_ + c * T_ + r) * H_ + h) * D_ + d0]);
    u16x4 hi;
    float sq = 0.f;
#pragma unroll
    for (int j = 0; j < 4; ++j) {
      const float xv = t4[j] * DN_;
      sq += xv * xv;
      hi[j] = f2bf(xv);
    }
    *reinterpret_cast<u16x4*>(&sm[FXK_ + r * 72 + d0]) = hi;
#pragma unroll
    for (int off = 1; off < 16; off <<= 1) sq += __shfl_xor(sq, off, 64);
    if ((tid & 15) == 0) diagk_s[r] = sq;
  }
  for (int i4 = tid; i4 < M_ * 16; i4 += 256) {
    const int m = i4 >> 4, d0 = (i4 & 15) * 4;
    const f32x4 t4 = *reinterpret_cast<const f32x4*>(&P[m * D_ + d0]);
    u16x4 hi;
#pragma unroll
    for (int j = 0; j < 4; ++j) hi[j] = f2bf(t4[j]);
    *reinterpret_cast<u16x4*>(&sm[FPH_ + m * 72 + d0]) = hi;
  }
#pragma unroll
  for (int it = 0; it < 4; ++it) {
    const int i4 = tid + 256 * it;
    const int t = i4 >> 4, d0 = (i4 & 15) * 4;
    const f32x4 t4 = *reinterpret_cast<const f32x4*>(
        &v[((size_t)(b * L_ + c * T_ + t) * H_ + h) * D_ + d0]);
#pragma unroll
    for (int j = 0; j < 4; ++j) sm[FVT_ + (d0 + j) * 72 + t] = f2bf(t4[j]);
  }
  __syncthreads();  // s1

  // ---- K dash MFMA + chunk max ----
  f32x4 acck[2][4];
#pragma unroll
  for (int i = 0; i < 2; ++i)
#pragma unroll
    for (int j = 0; j < 4; ++j) acck[i][j] = {0.f, 0.f, 0.f, 0.f};
#pragma unroll
  for (int kk = 0; kk < 2; ++kk) {
    short8 ah[2], bh8[4];
#pragma unroll
    for (int ti = 0; ti < 2; ++ti)
      ah[ti] = *reinterpret_cast<const short8*>(
          &sm[FXK_ + (rblk + ti * 16 + l15) * 72 + kk * 32 + l16 * 8]);
#pragma unroll
    for (int tj = 0; tj < 4; ++tj)
      bh8[tj] = *reinterpret_cast<const short8*>(
          &sm[FPH_ + (cblk + tj * 16 + l15) * 72 + kk * 32 + l16 * 8]);
#pragma unroll
    for (int ti = 0; ti < 2; ++ti)
#pragma unroll
      for (int tj = 0; tj < 4; ++tj)
        acck[ti][tj] = __builtin_amdgcn_mfma_f32_16x16x32_bf16(
            ah[ti], bh8[tj], acck[ti][tj], 0, 0, 0);
  }
  {
    float bm = -INFINITY;
#pragma unroll
    for (int ti = 0; ti < 2; ++ti)
#pragma unroll
      for (int tj = 0; tj < 4; ++tj)
#pragma unroll
        for (int j = 0; j < 4; ++j) bm = fmaxf(bm, acck[ti][tj][j]);
#pragma unroll
    for (int off = 1; off < 64; off <<= 1)
      bm = fmaxf(bm, __shfl_xor(bm, off, 64));
    if (lane == 0) red4_s[w] = bm;
  }
  __syncthreads();  // s2: red4 visible; dash reads of XK/PH done

  const float lmax =
      fmaxf(fmaxf(red4_s[0], red4_s[1]), fmaxf(red4_s[2], red4_s[3]));
  if (tid == 0) blockmax[sub] = lmax;
  // kpE epilogue -> KPT[m][t] (over PH)
#pragma unroll
  for (int ti = 0; ti < 2; ++ti)
#pragma unroll
    for (int j = 0; j < 4; ++j) {
      const int row = rblk + ti * 16 + l16 * 4 + j;
      const float sub2 = 0.5f * diagk_s[row] + lmax;
#pragma unroll
      for (int tj = 0; tj < 4; ++tj) {
        const int col = cblk + tj * 16 + l15;
        sm[FKPT_ + col * 72 + row] = f2bf(RATIO_ * expf(acck[ti][tj][j] - sub2));
      }
    }
  __syncthreads();  // s3: KPT visible

  // KV MFMA + ks + vsum + vt16 store
  f32x4 acc2[2][4];
#pragma unroll
  for (int i = 0; i < 2; ++i)
#pragma unroll
    for (int j = 0; j < 4; ++j) acc2[i][j] = {0.f, 0.f, 0.f, 0.f};
#pragma unroll
  for (int kk = 0; kk < 2; ++kk) {
    short8 av[2], bv[4];
#pragma unroll
    for (int ti = 0; ti < 2; ++ti)
      av[ti] = *reinterpret_cast<const short8*>(
          &sm[FVT_ + (rblk + ti * 16 + l15) * 72 + kk * 32 + l16 * 8]);
#pragma unroll
    for (int tj = 0; tj < 4; ++tj)
      bv[tj] = *reinterpret_cast<const short8*>(
          &sm[FKPT_ + (cblk + tj * 16 + l15) * 72 + kk * 32 + l16 * 8]);
#pragma unroll
    for (int ti = 0; ti < 2; ++ti)
#pragma unroll
      for (int tj = 0; tj < 4; ++tj)
        acc2[ti][tj] = __builtin_amdgcn_mfma_f32_16x16x32_bf16(
            av[ti], bv[tj], acc2[ti][tj], 0, 0, 0);
  }
  {
    unsigned short* vg = vt16 + (size_t)(bh * C_ + c) * (D_ * T_);
    for (int i8 = tid; i8 < D_ * 8; i8 += 256) {
      const int d = i8 >> 3, t0 = (i8 & 7) * 8;
      *reinterpret_cast<short8*>(&vg[d * T_ + t0]) =
          *reinterpret_cast<const short8*>(&sm[FVT_ + d * 72 + t0]);
    }
  }
  if (tid < M_) {  // ksE[m]
    float s = 0.f;
#pragma unroll
    for (int t8 = 0; t8 < 8; ++t8) {
      const short8 h8 =
          *reinterpret_cast<const short8*>(&sm[FKPT_ + tid * 72 + t8 * 8]);
#pragma unroll
      for (int j = 0; j < 8; ++j) s += bf2f((unsigned short)h8[j]);
    }
    ksc[(size_t)(bh * C_ + c) * M_ + tid] = s;
  }
  if (tid >= 128 && tid < 128 + D_) {  // Vsum[d]
    const int d = tid - 128;
    float s = 0.f;
#pragma unroll
    for (int t8 = 0; t8 < 8; ++t8) {
      const short8 h8 =
          *reinterpret_cast<const short8*>(&sm[FVT_ + d * 72 + t8 * 8]);
#pragma unroll
      for (int j = 0; j < 8; ++j) s += bf2f((unsigned short)h8[j]);
    }
    vsum[(size_t)(bh * C_ + c) * D_ + d] = s;
  }
  __syncthreads();  // s4: KPT reads done -> KVST may overwrite
#pragma unroll
  for (int ti = 0; ti < 2; ++ti)
#pragma unroll
    for (int j = 0; j < 4; ++j) {
      const int row = rblk + ti * 16 + l16 * 4 + j;  // d
#pragma unroll
      for (int tj = 0; tj < 4; ++tj) {
        const int col = cblk + tj * 16 + l15;  // m
        sm[FKVST_ + row * 136 + col] = f2bf(acc2[ti][tj][j]);
      }
    }
  __syncthreads();  // s5
  {
    unsigned short* ob = kvc16 + (size_t)(bh * C_ + c) * (M_ * D_);
    for (int i8 = tid; i8 < D_ * 16; i8 += 256) {
      const int d = i8 >> 4, m0 = (i8 & 15) * 8;
      *reinterpret_cast<short8*>(&ob[d * M_ + m0]) =
          *reinterpret_cast<const short8*>(&sm[FKVST_ + d * 136 + m0]);
    }
  }
}

// ---------------- prefix: unchanged ----------------
__global__ __launch_bounds__(256) void prefix_kernel(
    const unsigned short* __restrict__ kvc16,
    unsigned short* __restrict__ kvp16, float* __restrict__ ksc,
    const float* __restrict__ blockmax, const float* __restrict__ vsum) {
  __shared__ float bm_s[C_];
  __shared__ float sc_s[C_];
  __shared__ float vs_s[2][C_];
  const int bid = blockIdx.x;  // B*H*32
  const int ej = bid & 31, bh = bid >> 5;
  if (threadIdx.x < C_) bm_s[threadIdx.x] = blockmax[bh * C_ + threadIdx.x];
  if (threadIdx.x >= 64 && threadIdx.x < 64 + 2 * C_) {
    const int t = threadIdx.x - 64;
    const int ld = t >> 5, cc = t & 31;
    vs_s[ld][cc] = vsum[(size_t)(bh * C_ + cc) * D_ + ej * 2 + ld];
  }
  __syncthreads();
  if (threadIdx.x < C_) {
    float km = -INFINITY;
#pragma unroll
    for (int cc = 0; cc < C_; ++cc) km = fmaxf(km, bm_s[cc]);
    sc_s[threadIdx.x] = expf(bm_s[threadIdx.x] - km);
  }
  __syncthreads();
  const int e = ej * 256 + threadIdx.x;
  const int dl = threadIdx.x >> 7;
  float vals[C_];
#pragma unroll
  for (int cc = 0; cc < C_; ++cc)
    vals[cc] = bf2f(kvc16[(size_t)(bh * C_ + cc) * (M_ * D_) + e]) * sc_s[cc] +
               REPS_ * vs_s[dl][cc];
  float run = 0.f;
#pragma unroll
  for (int cc = 0; cc < C_; ++cc) {
    const float t = vals[cc];
    vals[cc] = run;
    run += t;
  }
#pragma unroll
  for (int cc = 0; cc < C_; ++cc)
    kvp16[(size_t)(bh * C_ + cc) * (M_ * D_) + e] = f2bf(vals[cc]);
  if (ej == 0 && threadIdx.x < M_) {
    const int m = threadIdx.x;
    float ks[C_];
#pragma unroll
    for (int cc = 0; cc < C_; ++cc)
      ks[cc] = ksc[(size_t)(bh * C_ + cc) * M_ + m] * sc_s[cc] + KEPS_;
    float rs = 0.f;
#pragma unroll
    for (int cc = 0; cc < C_; ++cc) {
      const float t = ks[cc];
      ks[cc] = rs;
      rs += t;
    }
#pragma unroll
    for (int cc = 0; cc < C_; ++cc)
      ksc[(size_t)(bh * C_ + cc) * M_ + m] = ks[cc];
  }
}

// ---------------- intra: recomputes feature maps ----------------
// LDS (shorts, 23040 = 46.1KB -> 3 blocks/CU): staging XQ[64][72]@0,
// XK[64][72]@4608, PH[128][72]@9216; aliases QP[64][136]@0 (over XQ+XK),
// KP[64][136]@9216 (over PH); S_s[64][72]@18432.
constexpr int IXQ_ = 0, IXK_ = 4608, IPH_ = 9216;
constexpr int IQP_ = 0, IKP_ = 9216, IS_ = 18432;

__global__ __launch_bounds__(256, 3) void intra_kernel(
    const float* __restrict__ q, const float* __restrict__ k,
    const float* __restrict__ P, const unsigned short* __restrict__ vt16,
    const unsigned short* __restrict__ kvp16, const float* __restrict__ ksp,
    const float* __restrict__ blockmax, float* __restrict__ out) {
  __shared__ __align__(16) unsigned short sm[23040];
  __shared__ float diagq_s[T_];
  __shared__ float diagk_s[T_];
  __shared__ float wred_s[2][T_];
  __shared__ float qs2_s[2][T_];
  __shared__ float ksp_s[M_];
  __shared__ float denp_s[4][T_];
  __shared__ float den_s[T_];
  __shared__ float bm_s[C_];

  const int bid = blockIdx.x;
  const int c = bid % C_, bh = bid / C_;
  const int b = bh >> 3, h = bh & 7;
  const int tid = threadIdx.x;
  const int w = tid >> 6, lane = tid & 63;
  const int l15 = lane & 15, l16 = lane >> 4;
  const int rblk = (w >> 1) * 32;      // row quadrant (all phases)
  const int cblkF = (w & 1) * 64;      // dash/epilogue col half
  const int cblkS = (w & 1) * 32;      // S col quadrant
  const int dblk = (w & 1) * 32;       // out d quadrant

  if (tid < C_) bm_s[tid] = blockmax[bh * C_ + tid];
  if (tid < M_) ksp_s[tid] = ksp[(size_t)(bh * C_ + c) * M_ + tid];

  // ---- stage q, k (bf16 + diag) and P ----
#pragma unroll
  for (int it = 0; it < 4; ++it) {
    const int i4 = tid + 256 * it;
    const int r = i4 >> 4, d0 = (i4 & 15) * 4;
    f32x4 t4 = *reinterpret_cast<const f32x4*>(
        &q[((size_t)(b * L_ + c * T_ + r) * H_ + h) * D_ + d0]);
    u16x4 hi;
    float sq = 0.f;
#pragma unroll
    for (int j = 0; j < 4; ++j) {
      const float xv = t4[j] * DN_;
      sq += xv * xv;
      hi[j] = f2bf(xv);
    }
    *reinterpret_cast<u16x4*>(&sm[IXQ_ + r * 72 + d0]) = hi;
#pragma unroll
    for (int off = 1; off < 16; off <<= 1) sq += __shfl_xor(sq, off, 64);
    if ((tid & 15) == 0) diagq_s[r] = sq;
  }
#pragma unroll
  for (int it = 0; it < 4; ++it) {
    const int i4 = tid + 256 * it;
    const int r = i4 >> 4, d0 = (i4 & 15) * 4;
    f32x4 t4 = *reinterpret_cast<const f32x4*>(
        &k[((size_t)(b * L_ + c * T_ + r) * H_ + h) * D_ + d0]);
    u16x4 hi;
    float sq = 0.f;
#pragma unroll
    for (int j = 0; j < 4; ++j) {
      const float xv = t4[j] * DN_;
      sq += xv * xv;
      hi[j] = f2bf(xv);
    }
    *reinterpret_cast<u16x4*>(&sm[IXK_ + r * 72 + d0]) = hi;
#pragma unroll
    for (int off = 1; off < 16; off <<= 1) sq += __shfl_xor(sq, off, 64);
    if ((tid & 15) == 0) diagk_s[r] = sq;
  }
  for (int i4 = tid; i4 < M_ * 16; i4 += 256) {
    const int m = i4 >> 4, d0 = (i4 & 15) * 4;
    const f32x4 t4 = *reinterpret_cast<const f32x4*>(&P[m * D_ + d0]);
    u16x4 hi;
#pragma unroll
    for (int j = 0; j < 4; ++j) hi[j] = f2bf(t4[j]);
    *reinterpret_cast<u16x4*>(&sm[IPH_ + m * 72 + d0]) = hi;
  }
  __syncthreads();  // s1

  // ---- dash MFMAs ----
  f32x4 accq[2][4], acck[2][4];
#pragma unroll
  for (int i = 0; i < 2; ++i)
#pragma unroll
    for (int j = 0; j < 4; ++j) {
      accq[i][j] = {0.f, 0.f, 0.f, 0.f};
      acck[i][j] = {0.f, 0.f, 0.f, 0.f};
    }
#pragma unroll
  for (int kk = 0; kk < 2; ++kk) {
    short8 aq[2], ak[2], bh8[4];
#pragma unroll
    for (int ti = 0; ti < 2; ++ti) {
      aq[ti] = *reinterpret_cast<const short8*>(
          &sm[IXQ_ + (rblk + ti * 16 + l15) * 72 + kk * 32 + l16 * 8]);
      ak[ti] = *reinterpret_cast<const short8*>(
          &sm[IXK_ + (rblk + ti * 16 + l15) * 72 + kk * 32 + l16 * 8]);
    }
#pragma unroll
    for (int tj = 0; tj < 4; ++tj)
      bh8[tj] = *reinterpret_cast<const short8*>(
          &sm[IPH_ + (cblkF + tj * 16 + l15) * 72 + kk * 32 + l16 * 8]);
#pragma unroll
    for (int ti = 0; ti < 2; ++ti)
#pragma unroll
      for (int tj = 0; tj < 4; ++tj) {
        accq[ti][tj] = __builtin_amdgcn_mfma_f32_16x16x32_bf16(
            aq[ti], bh8[tj], accq[ti][tj], 0, 0, 0);
        acck[ti][tj] = __builtin_amdgcn_mfma_f32_16x16x32_bf16(
            ak[ti], bh8[tj], acck[ti][tj], 0, 0, 0);
      }
  }
  {  // Q per-row max
    float rmax[2][4];
#pragma unroll
    for (int ti = 0; ti < 2; ++ti)
#pragma unroll
      for (int j = 0; j < 4; ++j) {
        float m0 = fmaxf(fmaxf(accq[ti][0][j], accq[ti][1][j]),
                         fmaxf(accq[ti][2][j], accq[ti][3][j]));
#pragma unroll
        for (int off = 1; off < 16; off <<= 1)
          m0 = fmaxf(m0, __shfl_xor(m0, off, 64));
        rmax[ti][j] = m0;
      }
    if (l15 == 0) {
#pragma unroll
      for (int ti = 0; ti < 2; ++ti)
#pragma unroll
        for (int j = 0; j < 4; ++j)
          wred_s[w & 1][rblk + ti * 16 + l16 * 4 + j] = rmax[ti][j];
    }
  }
  __syncthreads();  // s2: wred visible; dash reads of XQ/XK/PH done

  const float lmax = bm_s[c];  // same units as feat's kpE
  // ---- epilogues: qp (with eps) -> QP + qsum halves; kpE -> KP ----
#pragma unroll
  for (int ti = 0; ti < 2; ++ti)
#pragma unroll
    for (int j = 0; j < 4; ++j) {
      const int row = rblk + ti * 16 + l16 * 4 + j;
      const float subq =
          0.5f * diagq_s[row] + fmaxf(wred_s[0][row], wred_s[1][row]);
      const float subk = 0.5f * diagk_s[row] + lmax;
      float qsp = 0.f;
#pragma unroll
      for (int tj = 0; tj < 4; ++tj) {
        const int col = cblkF + tj * 16 + l15;
        const float qv = RATIO_ * (expf(accq[ti][tj][j] - subq) + EPSV_);
        qsp += qv;
        sm[IQP_ + row * 136 + col] = f2bf(qv);
        sm[IKP_ + row * 136 + col] =
            f2bf(RATIO_ * expf(acck[ti][tj][j] - subk));
      }
#pragma unroll
      for (int off = 1; off < 16; off <<= 1) qsp += __shfl_xor(qsp, off, 64);
      if (l15 == 0) qs2_s[w & 1][row] = qsp;
    }
  __syncthreads();  // s3: QP/KP/qs2 visible

  // ---- T14 prefetch PV B-frags (hidden under S MFMA + den) ----
  const unsigned short* kvt = kvp16 + (size_t)(bh * C_ + c) * (M_ * D_);
  const unsigned short* vg = vt16 + (size_t)(bh * C_ + c) * (D_ * T_);
  short8 vtr[2][2], kvr[4][2];
#pragma unroll
  for (int kk = 0; kk < 2; ++kk)
#pragma unroll
    for (int tj = 0; tj < 2; ++tj)
      vtr[kk][tj] = *reinterpret_cast<const short8*>(
          &vg[(dblk + tj * 16 + l15) * T_ + kk * 32 + l16 * 8]);
#pragma unroll
  for (int kk = 0; kk < 4; ++kk)
#pragma unroll
    for (int tj = 0; tj < 2; ++tj)
      kvr[kk][tj] = *reinterpret_cast<const short8*>(
          &kvt[(dblk + tj * 16 + l15) * M_ + kk * 32 + l16 * 8]);

  float km = -INFINITY;
#pragma unroll
  for (int cc = 0; cc < C_; ++cc) km = fmaxf(km, bm_s[cc]);
  const float sc = expf(bm_s[c] - km);

  // ---- S MFMA (A=QP rows t, B=KP rows t') ----
  f32x4 Sacc[2][2];
#pragma unroll
  for (int i = 0; i < 2; ++i)
#pragma unroll
    for (int j = 0; j < 2; ++j) Sacc[i][j] = {0.f, 0.f, 0.f, 0.f};
#pragma unroll
  for (int kk = 0; kk < 4; ++kk) {
    short8 af[2], bf[2];
#pragma unroll
    for (int ti = 0; ti < 2; ++ti)
      af[ti] = *reinterpret_cast<const short8*>(
          &sm[IQP_ + (rblk + ti * 16 + l15) * 136 + kk * 32 + l16 * 8]);
#pragma unroll
    for (int tj = 0; tj < 2; ++tj)
      bf[tj] = *reinterpret_cast<const short8*>(
          &sm[IKP_ + (cblkS + tj * 16 + l15) * 136 + kk * 32 + l16 * 8]);
#pragma unroll
    for (int ti = 0; ti < 2; ++ti)
#pragma unroll
      for (int tj = 0; tj < 2; ++tj)
        Sacc[ti][tj] = __builtin_amdgcn_mfma_f32_16x16x32_bf16(
            af[ti], bf[tj], Sacc[ti][tj], 0, 0, 0);
  }
#pragma unroll
  for (int ti = 0; ti < 2; ++ti)
#pragma unroll
    for (int tj = 0; tj < 2; ++tj)
#pragma unroll
      for (int j = 0; j < 4; ++j) {
        const int row = rblk + ti * 16 + l16 * 4 + j;
        const int col = cblkS + tj * 16 + l15;
        const float add = REPS_ * (qs2_s[0][row] + qs2_s[1][row]);
        const float sv = (col <= row) ? Sacc[ti][tj][j] * sc + add : 0.f;
        sm[IS_ + row * 72 + col] = f2bf(sv);
      }
  __syncthreads();  // s4: S_s visible

  {  // den partials: w0/w1 = S rowsum halves, w2/w3 = qp.ksp halves
    const int t = lane;
    float p = 0.f;
    if (w == 0) {
      for (int tp = 0; tp < 32; ++tp) p += bf2f(sm[IS_ + t * 72 + tp]);
    } else if (w == 1) {
      for (int tp = 32; tp < 64; ++tp) p += bf2f(sm[IS_ + t * 72 + tp]);
    } else if (w == 2) {
      for (int m = 0; m < 64; ++m)
        p += bf2f(sm[IQP_ + t * 136 + m]) * ksp_s[m];
    } else {
      for (int m = 64; m < 128; ++m)
        p += bf2f(sm[IQP_ + t * 136 + m]) * ksp_s[m];
    }
    denp_s[w][t] = p;
  }
  __syncthreads();  // s5
  if (tid < T_)
    den_s[tid] =
        denp_s[0][tid] + denp_s[1][tid] + denp_s[2][tid] + denp_s[3][tid];
  __syncthreads();  // s6

  // ---- PV: num = S@V^T + qp@KVp^T ----
  f32x4 Nacc[2][2];
#pragma unroll
  for (int i = 0; i < 2; ++i)
#pragma unroll
    for (int j = 0; j < 2; ++j) Nacc[i][j] = {0.f, 0.f, 0.f, 0.f};
#pragma unroll
  for (int kk = 0; kk < 2; ++kk) {
    short8 af[2];
#pragma unroll
    for (int ti = 0; ti < 2; ++ti)
      af[ti] = *reinterpret_cast<const short8*>(
          &sm[IS_ + (rblk + ti * 16 + l15) * 72 + kk * 32 + l16 * 8]);
#pragma unroll
    for (int ti = 0; ti < 2; ++ti)
#pragma unroll
      for (int tj = 0; tj < 2; ++tj)
        Nacc[ti][tj] = __builtin_amdgcn_mfma_f32_16x16x32_bf16(
            af[ti], vtr[kk][tj], Nacc[ti][tj], 0, 0, 0);
  }
#pragma unroll
  for (int kk = 0; kk < 4; ++kk) {
    short8 af[2];
#pragma unroll
    for (int ti = 0; ti < 2; ++ti)
      af[ti] = *reinterpret_cast<const short8*>(
          &sm[IQP_ + (rblk + ti * 16 + l15) * 136 + kk * 32 + l16 * 8]);
#pragma unroll
    for (int ti = 0; ti < 2; ++ti)
#pragma unroll
      for (int tj = 0; tj < 2; ++tj)
        Nacc[ti][tj] = __builtin_amdgcn_mfma_f32_16x16x32_bf16(
            af[ti], kvr[kk][tj], Nacc[ti][tj], 0, 0, 0);
  }

#pragma unroll
  for (int ti = 0; ti < 2; ++ti)
#pragma unroll
    for (int j = 0; j < 4; ++j) {
      const int row = rblk + ti * 16 + l16 * 4 + j;
      const float r = 1.f / den_s[row];
      float* orow = out + ((size_t)(b * L_ + c * T_ + row) * H_ + h) * D_;
#pragma unroll
      for (int tj = 0; tj < 2; ++tj) {
        const int col = dblk + tj * 16 + l15;
        orow[col] = Nacc[ti][tj][j] * r;
      }
    }
}

extern "C" void kernel_launch(void* const* d_in, const int* in_sizes, int n_in,
                              void* d_out, int out_size, void* d_ws,
                              size_t ws_size, hipStream_t stream) {
  const float* q = (const float*)d_in[0];
  const float* k = (const float*)d_in[1];
  const float* v = (const float*)d_in[2];
  const float* P = (const float*)d_in[3];
  float* out = (float*)d_out;

  // Workspace (~26 MB): blockmax | ksc | vsum | kvc16 | kvp16 | vt16
  float* ws = (float*)d_ws;
  float* blockmax = ws;                                   // 512
  float* ksc = blockmax + 512;                            // B*H*C*M
  float* vsum = ksc + (size_t)B_ * H_ * C_ * M_;          // B*H*C*D
  unsigned short* kvc16 = (unsigned short*)(vsum + (size_t)B_ * H_ * C_ * D_);
  unsigned short* kvp16 = kvc16 + (size_t)B_ * H_ * C_ * D_ * M_;
  unsigned short* vt16 = kvp16 + (size_t)B_ * H_ * C_ * D_ * M_;

  feat_kernel<<<B_ * H_ * C_, 256, 0, stream>>>(k, P, v, kvc16, ksc, vt16,
                                                blockmax, vsum);
  prefix_kernel<<<B_ * H_ * 32, 256, 0, stream>>>(kvc16, kvp16, ksc, blockmax,
                                                  vsum);
  intra_kernel<<<B_ * H_ * C_, 256, 0, stream>>>(q, k, P, vt16, kvp16, ksc,
                                                 blockmax, out);
}